// Round 7
// baseline (722.703 us; speedup 1.0000x reference)
//
#include <hip/hip_runtime.h>
#include <math.h>

#define DFF 512
#define NLAYER 2
#define TS_LD 132   // ts leading dim (bf16): 264B rows, measured 0 conflicts (R5)
#define CS_LD 130   // fdftmix c-tile stride (fp32)

typedef __bf16 bf16x8 __attribute__((ext_vector_type(8)));
typedef __bf16 bf16x4 __attribute__((ext_vector_type(4)));
typedef float f32x4 __attribute__((ext_vector_type(4)));

__device__ __forceinline__ float4 f4_load(const float* p) { return *(const float4*)p; }
__device__ __forceinline__ void f4_store(float* p, float4 v) { *(float4*)p = v; }
__device__ __forceinline__ float4 f4_zero() { return make_float4(0.f, 0.f, 0.f, 0.f); }
__device__ __forceinline__ float gelu_f(float x) {
    return 0.5f * x * (1.0f + erff(x * 0.70710678118654752440f));
}
// tanh-form gelu: max |err| vs exact ~3e-4; cheap (v_exp + v_rcp).
__device__ __forceinline__ float gelu_fast(float x) {
    float z = 1.5957691216f * (x + 0.044715f * x * x * x);   // 2*0.79788456*(...)
    float e = __expf(z);
    return x - x / (e + 1.0f);   // 0.5x(1+tanh(z/2)) == x*e/(e+1)
}
__device__ __forceinline__ void store_bf4(__bf16* p, float4 v) {
    __bf16 t[4] = {(__bf16)v.x, (__bf16)v.y, (__bf16)v.z, (__bf16)v.w};
    *(uint2*)p = *(uint2*)t;
}
__device__ __forceinline__ bf16x8 ld_b64x2(const __bf16* p) {
    bf16x4 lo = *(const bf16x4*)p;
    bf16x4 hi = *(const bf16x4*)(p + 4);
    return __builtin_shufflevector(lo, hi, 0, 1, 2, 3, 4, 5, 6, 7);
}

// ---------------------------------------------------------------------------
// Init: positional encoding fp32, Fttb bf16 [m2][t], Gtb bf16 [t][m2].
// ---------------------------------------------------------------------------
__global__ __launch_bounds__(256) void k_init(float* __restrict__ pe,
                                              __bf16* __restrict__ Fttb,
                                              __bf16* __restrict__ Gtb) {
    int idx = blockIdx.x * 256 + threadIdx.x;   // 0..65535
    {
        int l = idx >> 7, d = idx & 127;
        int j = d >> 1;
        double div = exp((double)(2 * j) * (-log(10000.0) / 128.0));
        double a = (double)l * div;
        pe[idx] = (d & 1) ? (float)cos(a) : (float)sin(a);
    }
    {
        int m2 = idx >> 9, t = idx & 511;
        int m = m2 >> 1;
        int r = (m * t) & 511;
        double ang = (double)r * (6.283185307179586476925287 / 512.0);
        float cv = (float)cos(ang), sv = (float)sin(ang);
        float f = (m2 & 1) ? -sv : cv;
        Fttb[idx] = (__bf16)f;
        float s = (m == 0) ? (1.0f / 512.0f) : (2.0f / 512.0f);
        Gtb[t * 128 + m2] = (__bf16)(f * s);
    }
}

// ---------------------------------------------------------------------------
// Cast+transpose weights to bf16.
// ---------------------------------------------------------------------------
__global__ __launch_bounds__(256) void k_castw(const float* __restrict__ Wq,
                                               const float* __restrict__ Wo,
                                               const float* __restrict__ W1,
                                               const float* __restrict__ W2,
                                               const float* __restrict__ cw,
                                               __bf16* __restrict__ wbf,
                                               __bf16* __restrict__ cwtk) {
    int i = blockIdx.x * 256 + threadIdx.x;   // < 376832
    if (i < 65536) {
        int r = i & 16383, l = (i >> 14) & 1;
        int n = r >> 7, k = r & 127;
        const float* W = (i >= 32768) ? Wo : Wq;
        wbf[i] = (__bf16)W[l * 16384 + k * 128 + n];
    } else if (i < 196608) {
        int j = i - 65536;
        int l = j >> 16, r = j & 65535;
        int f = r >> 7, k = r & 127;
        wbf[i] = (__bf16)W1[l * 65536 + k * 512 + f];
    } else if (i < 327680) {
        int j = i - 196608;
        int l = j >> 16, r = j & 65535;
        int n = r >> 9, f = r & 511;
        wbf[i] = (__bf16)W2[l * 65536 + f * 128 + n];
    } else if (i < 376832) {
        int j = i - 327680;          // s*16384 + d*128 + ii
        int s = j >> 14, r = j & 16383;
        int d = r >> 7, ii = r & 127;
        cwtk[j] = (__bf16)cw[(d * 128 + ii) * 3 + s];
    }
}

// ---------------------------------------------------------------------------
// Transpose x_enc (B,D,L) fp32 -> xt (B,L,D) bf16.
// ---------------------------------------------------------------------------
__global__ __launch_bounds__(256) void k_xpose(const float* __restrict__ xe,
                                               __bf16* __restrict__ xt) {
    __shared__ float ts[128][65];
    const int b = blockIdx.y, l0 = blockIdx.x * 64;
    for (int idx = threadIdx.x; idx < 128 * 16; idx += 256) {
        int d = idx >> 4, c4 = idx & 15;
        float4 v = f4_load(&xe[((size_t)b * 128 + d) * 512 + l0 + c4 * 4]);
        ts[d][c4 * 4 + 0] = v.x; ts[d][c4 * 4 + 1] = v.y;
        ts[d][c4 * 4 + 2] = v.z; ts[d][c4 * 4 + 3] = v.w;
    }
    __syncthreads();
#pragma unroll
    for (int p = 0; p < 4; ++p) {
        int l = (threadIdx.x >> 4) + p * 16;
        int d0 = (threadIdx.x & 15) * 8;
        __bf16 tmp[8];
#pragma unroll
        for (int j = 0; j < 8; ++j) tmp[j] = (__bf16)ts[d0 + j][l];
        *(uint4*)&xt[((size_t)b * 512 + l0 + l) * 128 + d0] = *(uint4*)tmp;
    }
}

// ---------------------------------------------------------------------------
// MFMA embed, 64-row blocks: per-wave 32x64 tile, acc=32 VGPR.
// ---------------------------------------------------------------------------
__global__ __launch_bounds__(256, 4) void k_embed_m(const __bf16* __restrict__ xt,
                                                    const __bf16* __restrict__ cwtk,
                                                    const float* __restrict__ pe,
                                                    float* __restrict__ h,
                                                    __bf16* __restrict__ hb) {
    const int b = blockIdx.x >> 3, l0 = (blockIdx.x & 7) * 64;
    const int lane = threadIdx.x & 63, wid = threadIdx.x >> 6;
    const int wrow = (wid & 1) * 32, wcol = (wid >> 1) * 64;
    const int m16 = lane & 15, quad = lane >> 4;
    f32x4 acc[2][4];
#pragma unroll
    for (int a = 0; a < 2; ++a)
#pragma unroll
        for (int bb = 0; bb < 4; ++bb) acc[a][bb] = {0.f, 0.f, 0.f, 0.f};
#pragma unroll
    for (int s = 0; s < 3; ++s) {
#pragma unroll
        for (int ks = 0; ks < 4; ++ks) {
            const int ko = ks * 32 + quad * 8;
            bf16x8 af[2], bfr[4];
#pragma unroll
            for (int rt = 0; rt < 2; ++rt) {
                int gl = (l0 + wrow + rt * 16 + m16 + s - 1) & 511;
                af[rt] = *(const bf16x8*)&xt[(((size_t)b * 512 + gl) << 7) + ko];
            }
#pragma unroll
            for (int ct = 0; ct < 4; ++ct)
                bfr[ct] = *(const bf16x8*)&cwtk[((size_t)(s * 128 + wcol + ct * 16 + m16) << 7) + ko];
#pragma unroll
            for (int rt = 0; rt < 2; ++rt)
#pragma unroll
                for (int ct = 0; ct < 4; ++ct)
                    acc[rt][ct] = __builtin_amdgcn_mfma_f32_16x16x32_bf16(
                        af[rt], bfr[ct], acc[rt][ct], 0, 0, 0);
        }
    }
#pragma unroll
    for (int ct = 0; ct < 4; ++ct) {
        int gcol = wcol + ct * 16 + m16;
#pragma unroll
        for (int rt = 0; rt < 2; ++rt)
#pragma unroll
            for (int r = 0; r < 4; ++r) {
                int l = l0 + wrow + rt * 16 + quad * 4 + r;
                float v = acc[rt][ct][r] + pe[l * 128 + gcol];
                size_t gi = (((size_t)b * 512 + l) << 7) + gcol;
                h[gi] = v;
                hb[gi] = (__bf16)v;
            }
    }
}

// ---------------------------------------------------------------------------
// q-proj transposed, 64-row blocks: qT[n][row] = (X @ Wq + bq)^T, bf16 out.
// ---------------------------------------------------------------------------
__global__ __launch_bounds__(256, 4) void k_qprojT(const __bf16* __restrict__ Xb,
                                                   const __bf16* __restrict__ Wt,
                                                   const float* __restrict__ bias,
                                                   __bf16* __restrict__ qT) {
    const int rowBase = blockIdx.x * 64;
    const int lane = threadIdx.x & 63, wid = threadIdx.x >> 6;
    const int wn = (wid & 1) * 64, wr = (wid >> 1) * 32;
    const int m16 = lane & 15, quad = lane >> 4;
    f32x4 acc[4][2];
#pragma unroll
    for (int a = 0; a < 4; ++a)
#pragma unroll
        for (int b = 0; b < 2; ++b) acc[a][b] = {0.f, 0.f, 0.f, 0.f};
#pragma unroll
    for (int ks = 0; ks < 4; ++ks) {
        const int ko = ks * 32 + quad * 8;
        bf16x8 wf[4], xf[2];
#pragma unroll
        for (int rt = 0; rt < 4; ++rt)
            wf[rt] = *(const bf16x8*)&Wt[((size_t)(wn + rt * 16 + m16) << 7) + ko];
#pragma unroll
        for (int ct = 0; ct < 2; ++ct)
            xf[ct] = *(const bf16x8*)&Xb[((size_t)(rowBase + wr + ct * 16 + m16) << 7) + ko];
#pragma unroll
        for (int rt = 0; rt < 4; ++rt)
#pragma unroll
            for (int ct = 0; ct < 2; ++ct)
                acc[rt][ct] = __builtin_amdgcn_mfma_f32_16x16x32_bf16(
                    wf[rt], xf[ct], acc[rt][ct], 0, 0, 0);
    }
#pragma unroll
    for (int rt = 0; rt < 4; ++rt)
#pragma unroll
        for (int r = 0; r < 4; ++r) {
            int n = wn + rt * 16 + quad * 4 + r;
            float bv = bias[n];
#pragma unroll
            for (int ct = 0; ct < 2; ++ct) {
                int grow = rowBase + wr + ct * 16 + m16;
                qT[(size_t)n * 65536 + grow] = (__bf16)(acc[rt][ct][r] + bv);
            }
        }
}

// ---------------------------------------------------------------------------
// Fused forward-DFT + mode mix.
// ---------------------------------------------------------------------------
__global__ __launch_bounds__(128) void k_fdftmix(const __bf16* __restrict__ qT,
                                                 const __bf16* __restrict__ Fttb,
                                                 const float* __restrict__ fwr,
                                                 const float* __restrict__ fwi,
                                                 __bf16* __restrict__ ddb) {
    __shared__ float cs[32][CS_LD];
    const int b = blockIdx.y, d0 = blockIdx.x * 32;
    const int lane = threadIdx.x & 63, wid = threadIdx.x >> 6;
    const int wm = wid * 64;
    const int m16 = lane & 15, quad = lane >> 4;
    f32x4 acc[2][4];
#pragma unroll
    for (int a = 0; a < 2; ++a)
#pragma unroll
        for (int bb = 0; bb < 4; ++bb) acc[a][bb] = {0.f, 0.f, 0.f, 0.f};
    for (int ks = 0; ks < 16; ++ks) {
        const int ko = ks * 32 + quad * 8;
        bf16x8 af[2], bf[4];
#pragma unroll
        for (int rt = 0; rt < 2; ++rt)
            af[rt] = *(const bf16x8*)&qT[(size_t)(d0 + rt * 16 + m16) * 65536 + b * 512 + ko];
#pragma unroll
        for (int ct = 0; ct < 4; ++ct)
            bf[ct] = *(const bf16x8*)&Fttb[(size_t)(wm + ct * 16 + m16) * 512 + ko];
#pragma unroll
        for (int rt = 0; rt < 2; ++rt)
#pragma unroll
            for (int ct = 0; ct < 4; ++ct)
                acc[rt][ct] = __builtin_amdgcn_mfma_f32_16x16x32_bf16(
                    af[rt], bf[ct], acc[rt][ct], 0, 0, 0);
    }
#pragma unroll
    for (int rt = 0; rt < 2; ++rt)
#pragma unroll
        for (int ct = 0; ct < 4; ++ct)
#pragma unroll
            for (int r = 0; r < 4; ++r)
                cs[rt * 16 + quad * 4 + r][wm + ct * 16 + m16] = acc[rt][ct][r];
    __syncthreads();
    const int m = threadIdx.x & 63, og = threadIdx.x >> 6;   // og in {0,1}
#pragma unroll
    for (int lh = 0; lh < 2; ++lh) {
        int hh = (d0 >> 4) + lh;
#pragma unroll
        for (int oi = 0; oi < 8; ++oi) {
            int o = og * 8 + oi;
            float dr = 0.f, di = 0.f;
#pragma unroll
            for (int e = 0; e < 16; ++e) {
                float2 cv = *(const float2*)&cs[lh * 16 + e][2 * m];
                float wr = fwr[(((size_t)hh * 16 + e) * 16 + o) * 64 + m];
                float wi = fwi[(((size_t)hh * 16 + e) * 16 + o) * 64 + m];
                dr += cv.x * wr - cv.y * wi;
                di += cv.x * wi + cv.y * wr;
            }
            __bf16 t2[2] = {(__bf16)dr, (__bf16)di};
            *(uint*)&ddb[((size_t)b * 128 + hh * 16 + o) * 128 + 2 * m] = *(uint*)t2;
        }
    }
}

// ---------------------------------------------------------------------------
// Inverse DFT via MFMA: per-wave 64t x 32ho.
// ---------------------------------------------------------------------------
__global__ __launch_bounds__(256, 4) void k_idft_m(const __bf16* __restrict__ ddb,
                                                   const __bf16* __restrict__ Gtb,
                                                   __bf16* __restrict__ y) {
    const int b = blockIdx.y;
    const int t0 = (blockIdx.x & 3) * 128, hob = (blockIdx.x >> 2) * 64;
    const int lane = threadIdx.x & 63, wid = threadIdx.x >> 6;
    const int wt = (wid & 1) * 64, wh = (wid >> 1) * 32;
    const int m16 = lane & 15, quad = lane >> 4;
    f32x4 acc[4][2];
#pragma unroll
    for (int a = 0; a < 4; ++a)
#pragma unroll
        for (int bb = 0; bb < 2; ++bb) acc[a][bb] = {0.f, 0.f, 0.f, 0.f};
#pragma unroll
    for (int ks = 0; ks < 4; ++ks) {
        const int ko = ks * 32 + quad * 8;
        bf16x8 af[4], bf[2];
#pragma unroll
        for (int rt = 0; rt < 4; ++rt)
            af[rt] = *(const bf16x8*)&Gtb[(size_t)(t0 + wt + rt * 16 + m16) * 128 + ko];
#pragma unroll
        for (int ct = 0; ct < 2; ++ct)
            bf[ct] = *(const bf16x8*)&ddb[((size_t)b * 128 + hob + wh + ct * 16 + m16) * 128 + ko];
#pragma unroll
        for (int rt = 0; rt < 4; ++rt)
#pragma unroll
            for (int ct = 0; ct < 2; ++ct)
                acc[rt][ct] = __builtin_amdgcn_mfma_f32_16x16x32_bf16(
                    af[rt], bf[ct], acc[rt][ct], 0, 0, 0);
    }
#pragma unroll
    for (int rt = 0; rt < 4; ++rt)
#pragma unroll
        for (int ct = 0; ct < 2; ++ct) {
            int ho = hob + wh + ct * 16 + m16;
            int tb = t0 + wt + rt * 16 + quad * 4;
            __bf16 tmp[4] = {(__bf16)acc[rt][ct][0], (__bf16)acc[rt][ct][1],
                             (__bf16)acc[rt][ct][2], (__bf16)acc[rt][ct][3]};
            *(uint2*)&y[((size_t)b * 128 + ho) * 512 + tb] = *(uint2*)tmp;
        }
}

// ---------------------------------------------------------------------------
// MFMA GEMM, 64-row blocks: out = Xb @ W + bias (+R), per-wave 32x64.
// ---------------------------------------------------------------------------
template <bool RES>
__global__ __launch_bounds__(256, 4) void k_mgemm(const __bf16* __restrict__ Xb,
                                                  const __bf16* __restrict__ Wt,
                                                  const float* __restrict__ bias,
                                                  const float* __restrict__ R,
                                                  float* __restrict__ out) {
    const int rowBase = blockIdx.x * 64;
    const int lane = threadIdx.x & 63, wid = threadIdx.x >> 6;
    const int wrow = (wid & 1) * 32, wcol = (wid >> 1) * 64;
    const int m16 = lane & 15, quad = lane >> 4;
    f32x4 acc[2][4];
#pragma unroll
    for (int a = 0; a < 2; ++a)
#pragma unroll
        for (int b = 0; b < 4; ++b) acc[a][b] = {0.f, 0.f, 0.f, 0.f};
#pragma unroll
    for (int ks = 0; ks < 4; ++ks) {
        const int ko = ks * 32 + quad * 8;
        bf16x8 af[2], bfr[4];
#pragma unroll
        for (int rt = 0; rt < 2; ++rt)
            af[rt] = *(const bf16x8*)&Xb[((size_t)(rowBase + wrow + rt * 16 + m16) << 7) + ko];
#pragma unroll
        for (int ct = 0; ct < 4; ++ct)
            bfr[ct] = *(const bf16x8*)&Wt[((size_t)(wcol + ct * 16 + m16) << 7) + ko];
#pragma unroll
        for (int rt = 0; rt < 2; ++rt)
#pragma unroll
            for (int ct = 0; ct < 4; ++ct)
                acc[rt][ct] = __builtin_amdgcn_mfma_f32_16x16x32_bf16(
                    af[rt], bfr[ct], acc[rt][ct], 0, 0, 0);
    }
#pragma unroll
    for (int ct = 0; ct < 4; ++ct) {
        int gcol = wcol + ct * 16 + m16;
        float bv = bias[gcol];
#pragma unroll
        for (int rt = 0; rt < 2; ++rt)
#pragma unroll
            for (int r = 0; r < 4; ++r) {
                size_t gi = ((size_t)(rowBase + wrow + rt * 16 + quad * 4 + r) << 7) + gcol;
                float v = acc[rt][ct][r] + bv;
                if (RES) v += R[gi];
                out[gi] = v;
            }
    }
}

// ---------------------------------------------------------------------------
// MFMA FFN, 64-row blocks, X register-resident: out = Xf + gelu(X@W1) @ W2.
// Per-wave 32x64 tiles; X fragments (32 rows x K=128 = 32 VGPR) loaded ONCE
// and held across all f0 chunks -> no global X re-reads (R6's L2-thrash fix).
// ---------------------------------------------------------------------------
__global__ __launch_bounds__(256, 4) void k_ffnm(const __bf16* __restrict__ Xb,
                                                 const float* __restrict__ Xf,
                                                 const __bf16* __restrict__ W1t,
                                                 const __bf16* __restrict__ W2t,
                                                 float* __restrict__ out) {
    __shared__ __align__(16) __bf16 ts[64 * TS_LD];
    const int rowBase = blockIdx.x * 64;
    const int lane = threadIdx.x & 63, wid = threadIdx.x >> 6;
    const int wrow = (wid & 1) * 32, wcol = (wid >> 1) * 64;
    const int m16 = lane & 15, quad = lane >> 4;
    // Preload X fragments for this wave's 32 rows, all K=128.
    bf16x8 xfr[2][4];
#pragma unroll
    for (int rt = 0; rt < 2; ++rt)
#pragma unroll
        for (int ks = 0; ks < 4; ++ks)
            xfr[rt][ks] = *(const bf16x8*)&Xb[
                ((size_t)(rowBase + wrow + rt * 16 + m16) << 7) + ks * 32 + quad * 8];
    f32x4 acc2[2][4];
#pragma unroll
    for (int a = 0; a < 2; ++a)
#pragma unroll
        for (int b = 0; b < 4; ++b) acc2[a][b] = {0.f, 0.f, 0.f, 0.f};

    for (int f0 = 0; f0 < DFF; f0 += 128) {
        f32x4 c1[2][4];
#pragma unroll
        for (int a = 0; a < 2; ++a)
#pragma unroll
            for (int b = 0; b < 4; ++b) c1[a][b] = {0.f, 0.f, 0.f, 0.f};
#pragma unroll
        for (int ks = 0; ks < 4; ++ks) {
            const int ko = ks * 32 + quad * 8;
            bf16x8 bfr[4];
#pragma unroll
            for (int ct = 0; ct < 4; ++ct)
                bfr[ct] = *(const bf16x8*)&W1t[((size_t)(f0 + wcol + ct * 16 + m16) << 7) + ko];
#pragma unroll
            for (int rt = 0; rt < 2; ++rt)
#pragma unroll
                for (int ct = 0; ct < 4; ++ct)
                    c1[rt][ct] = __builtin_amdgcn_mfma_f32_16x16x32_bf16(
                        xfr[rt][ks], bfr[ct], c1[rt][ct], 0, 0, 0);
        }
#pragma unroll
        for (int rt = 0; rt < 2; ++rt)
#pragma unroll
            for (int ct = 0; ct < 4; ++ct)
#pragma unroll
                for (int r = 0; r < 4; ++r) {
                    int lrow = wrow + rt * 16 + quad * 4 + r;
                    int lcol = wcol + ct * 16 + m16;
                    ts[lrow * TS_LD + lcol] = (__bf16)gelu_fast(c1[rt][ct][r]);
                }
        __syncthreads();
#pragma unroll
        for (int ks = 0; ks < 4; ++ks) {
            const int ko = ks * 32 + quad * 8;
            bf16x8 af[2], bfr[4];
#pragma unroll
            for (int rt = 0; rt < 2; ++rt)
                af[rt] = ld_b64x2(&ts[(wrow + rt * 16 + m16) * TS_LD + ko]);
#pragma unroll
            for (int ct = 0; ct < 4; ++ct)
                bfr[ct] = *(const bf16x8*)&W2t[((size_t)(wcol + ct * 16 + m16) << 9) + f0 + ko];
#pragma unroll
            for (int rt = 0; rt < 2; ++rt)
#pragma unroll
                for (int ct = 0; ct < 4; ++ct)
                    acc2[rt][ct] = __builtin_amdgcn_mfma_f32_16x16x32_bf16(
                        af[rt], bfr[ct], acc2[rt][ct], 0, 0, 0);
        }
        __syncthreads();
    }
#pragma unroll
    for (int ct = 0; ct < 4; ++ct) {
        int gcol = wcol + ct * 16 + m16;
#pragma unroll
        for (int rt = 0; rt < 2; ++rt)
#pragma unroll
            for (int r = 0; r < 4; ++r) {
                size_t gi = ((size_t)(rowBase + wrow + rt * 16 + quad * 4 + r) << 7) + gcol;
                out[gi] = acc2[rt][ct][r] + Xf[gi];
            }
    }
}

// ---------------------------------------------------------------------------
// Series decomp, d-split: block = 128 l x 64 d, LDS 152x64 fp32 (38 KB).
// ---------------------------------------------------------------------------
__global__ __launch_bounds__(256) void k_decomp(const float* __restrict__ X,
                                                float* __restrict__ out,
                                                __bf16* __restrict__ outb) {
    __shared__ float xs[152][64];
    const int b = blockIdx.y;
    const int l0 = (blockIdx.x >> 1) * 128, dh = (blockIdx.x & 1) * 64;
    for (int idx = threadIdx.x; idx < 152 * 16; idx += 256) {
        int r = idx >> 4, c4 = idx & 15;
        int gl = l0 - 12 + r;
        gl = gl < 0 ? 0 : (gl > 511 ? 511 : gl);
        f4_store(&xs[r][c4 * 4],
                 f4_load(&X[((size_t)b * 512 + gl) * 128 + dh + c4 * 4]));
    }
    __syncthreads();
    const int dg = threadIdx.x & 15, lg = threadIdx.x >> 4;
    const int d0 = dg * 4, base = lg * 8;
    float4 s = f4_zero();
#pragma unroll
    for (int w = 0; w < 25; ++w) {
        float4 v = f4_load(&xs[base + w][d0]);
        s.x += v.x; s.y += v.y; s.z += v.z; s.w += v.w;
    }
    const float inv = 1.0f / 25.0f;
#pragma unroll
    for (int i = 0; i < 8; ++i) {
        int t = base + 12 + i;
        float4 x = f4_load(&xs[t][d0]);
        float4 o = make_float4(x.x - s.x * inv, x.y - s.y * inv,
                               x.z - s.z * inv, x.w - s.w * inv);
        size_t gi = ((size_t)b * 512 + l0 + lg * 8 + i) * 128 + dh + d0;
        f4_store(&out[gi], o);
        store_bf4(&outb[gi], o);
        if (i < 7) {
            float4 a = f4_load(&xs[base + 25 + i][d0]);
            float4 r = f4_load(&xs[base + i][d0]);
            s.x += a.x - r.x; s.y += a.y - r.y; s.z += a.z - r.z; s.w += a.w - r.w;
        }
    }
}

// ---------------------------------------------------------------------------
// LayerNorm over D=128; one wave per row.
// ---------------------------------------------------------------------------
__global__ __launch_bounds__(256) void k_ln(const float* __restrict__ X,
                                            const float* __restrict__ g,
                                            const float* __restrict__ bb,
                                            float* __restrict__ out) {
    const int row = blockIdx.x * 4 + (threadIdx.x >> 6);
    const int lane = threadIdx.x & 63;
    float2 v = *(const float2*)&X[(size_t)row * 128 + lane * 2];
    float s = v.x + v.y, ss = v.x * v.x + v.y * v.y;
#pragma unroll
    for (int o = 32; o; o >>= 1) {
        s += __shfl_xor(s, o);
        ss += __shfl_xor(ss, o);
    }
    float mu = s * (1.0f / 128.0f);
    float var = ss * (1.0f / 128.0f) - mu * mu;
    float rstd = rsqrtf(var + 1e-5f);
    float2 gg = *(const float2*)&g[lane * 2];
    float2 bv = *(const float2*)&bb[lane * 2];
    float2 o;
    o.x = (v.x - mu) * rstd * gg.x + bv.x;
    o.y = (v.y - mu) * rstd * gg.y + bv.y;
    *(float2*)&out[(size_t)row * 128 + lane * 2] = o;
}

__global__ __launch_bounds__(128) void k_colmean(const float* __restrict__ X,
                                                 float* __restrict__ cm) {
    const int b = blockIdx.y, l0 = blockIdx.x * 64, d = threadIdx.x;
    float s = 0.f;
    for (int l = l0; l < l0 + 64; ++l) s += X[((size_t)b * 512 + l) * 128 + d];
    atomicAdd(&cm[b * 128 + d], s);
}

__global__ __launch_bounds__(128) void k_final(const float* __restrict__ hn,
                                               const float* __restrict__ cm,
                                               const float* __restrict__ mark,
                                               const float* __restrict__ pw,
                                               const float* __restrict__ pb,
                                               float* __restrict__ out) {
    const int b = blockIdx.y, l0 = blockIdx.x * 128, d = threadIdx.x;
    const float c = cm[b * 128 + d] * (1.0f / 512.0f);
    float acc = 0.f;
    for (int l = l0; l < l0 + 128; ++l) {
        float v = hn[((size_t)b * 512 + l) * 128 + d] - c;
        acc += gelu_f(v) * mark[((size_t)b * 128 + d) * 512 + l] * pw[l * 128 + d];
    }
    __shared__ float red[2];
#pragma unroll
    for (int o = 32; o; o >>= 1) acc += __shfl_xor(acc, o);
    if ((threadIdx.x & 63) == 0) red[threadIdx.x >> 6] = acc;
    __syncthreads();
    if (threadIdx.x == 0) {
        float tot = red[0] + red[1];
        if (blockIdx.x == 0) tot += pb[0];
        atomicAdd(&out[b], tot);
    }
}

// ---------------------------------------------------------------------------
extern "C" void kernel_launch(void* const* d_in, const int* in_sizes, int n_in,
                              void* d_out, int out_size, void* d_ws, size_t ws_size,
                              hipStream_t stream) {
    const float* xe   = (const float*)d_in[0];
    const float* mark = (const float*)d_in[1];
    const float* cw   = (const float*)d_in[4];
    const float* Wq   = (const float*)d_in[5];
    const float* bq   = (const float*)d_in[6];
    const float* Wo   = (const float*)d_in[7];
    const float* bo   = (const float*)d_in[8];
    const float* fwr  = (const float*)d_in[9];
    const float* fwi  = (const float*)d_in[10];
    const float* W1   = (const float*)d_in[11];
    const float* W2   = (const float*)d_in[12];
    const float* lng  = (const float*)d_in[13];
    const float* lnb  = (const float*)d_in[14];
    const float* pw   = (const float*)d_in[15];
    const float* pb   = (const float*)d_in[16];
    float* out = (float*)d_out;

    // Workspace layout (float-slot offsets). Total ~101.9 MB.
    float* ws    = (float*)d_ws;
    __bf16* Fttb = (__bf16*)ws;              // 65536 bf16
    __bf16* Gtb  = (__bf16*)(ws + 65536);    // 65536 bf16
    float* h     = ws + 131072;              // 8388608 fp32 state
    float* bufA  = ws + 8519680;             // 8388608 (xt | qT+ddb | s | hn)
    __bf16* hb   = (__bf16*)(ws + 16908288); // 8388608 bf16
    float* yrg   = ws + 21102592;            // 4194304 (pe+cwtk | yb)
    float* cm    = ws + 25296896;            // 16384
    __bf16* wbf  = (__bf16*)(ws + 25313280); // 327680 bf16
    float* pe    = yrg;                      // [0,65536) of yrg
    __bf16* cwtk = (__bf16*)(yrg + 65536);   // 49152 bf16 (dead after embed)
    __bf16* yb   = (__bf16*)yrg;             // overlays pe/cwtk after embed
    __bf16* xt   = (__bf16*)bufA;            // dead after embed
    __bf16* qT   = (__bf16*)bufA;            // 8388608 bf16 (dead after fdftmix)
    __bf16* ddb  = (__bf16*)(bufA + 4194304);// 2097152 bf16
    __bf16* Wqt  = wbf;
    __bf16* Wot  = wbf + 32768;
    __bf16* W1t  = wbf + 65536;
    __bf16* W2t  = wbf + 196608;

    k_init<<<256, 256, 0, stream>>>(pe, Fttb, Gtb);
    k_castw<<<1472, 256, 0, stream>>>(Wq, Wo, W1, W2, cw, wbf, cwtk);
    k_xpose<<<dim3(8, 128), 256, 0, stream>>>(xe, xt);
    k_embed_m<<<1024, 256, 0, stream>>>(xt, cwtk, pe, h, hb);
    for (int l = 0; l < NLAYER; ++l) {
        k_qprojT<<<1024, 256, 0, stream>>>(hb, Wqt + l * 16384, bq + l * 128, qT);
        k_fdftmix<<<dim3(4, 128), 128, 0, stream>>>(qT, Fttb, fwr + l * 131072,
                                                    fwi + l * 131072, ddb);
        k_idft_m<<<dim3(8, 128), 256, 0, stream>>>(ddb, Gtb, yb);
        k_mgemm<true><<<1024, 256, 0, stream>>>(yb, Wot + l * 16384, bo + l * 128,
                                                h, bufA);
        k_decomp<<<dim3(8, 128), 256, 0, stream>>>(bufA, h, hb);
        k_ffnm<<<1024, 256, 0, stream>>>(hb, h, W1t + l * 65536, W2t + l * 65536, bufA);
        k_decomp<<<dim3(8, 128), 256, 0, stream>>>(bufA, h, hb);
    }
    k_ln<<<16384, 256, 0, stream>>>(h, lng, lnb, bufA);
    hipMemsetAsync(cm, 0, 16384 * sizeof(float), stream);
    k_colmean<<<dim3(8, 128), 128, 0, stream>>>(bufA, cm);
    hipMemsetAsync(d_out, 0, 128 * sizeof(float), stream);
    k_final<<<dim3(4, 128), 128, 0, stream>>>(bufA, cm, mark, pw, pb, out);

    (void)in_sizes; (void)n_in; (void)out_size; (void)ws_size;
}

// Round 8
// 675.389 us; speedup vs baseline: 1.0701x; 1.0701x over previous
//
#include <hip/hip_runtime.h>
#include <math.h>

#define DFF 512
#define NLAYER 2
#define CS_LD 130   // fdftmix c-tile stride (fp32)
#define SS_LD 130   // fused-decomp s-tile stride (fp32): 2-way-free writes
#define TS2_LD 68   // ffd gelu-tile stride (bf16)

typedef __bf16 bf16x8 __attribute__((ext_vector_type(8)));
typedef __bf16 bf16x4 __attribute__((ext_vector_type(4)));
typedef float f32x4 __attribute__((ext_vector_type(4)));

__device__ __forceinline__ float4 f4_load(const float* p) { return *(const float4*)p; }
__device__ __forceinline__ void f4_store(float* p, float4 v) { *(float4*)p = v; }
__device__ __forceinline__ float4 f4_zero() { return make_float4(0.f, 0.f, 0.f, 0.f); }
__device__ __forceinline__ float gelu_f(float x) {
    return 0.5f * x * (1.0f + erff(x * 0.70710678118654752440f));
}
// tanh-form gelu: max |err| vs exact ~3e-4; cheap (v_exp + v_rcp).
__device__ __forceinline__ float gelu_fast(float x) {
    float z = 1.5957691216f * (x + 0.044715f * x * x * x);
    float e = __expf(z);
    return x - x / (e + 1.0f);
}
__device__ __forceinline__ void store_bf4(__bf16* p, float4 v) {
    __bf16 t[4] = {(__bf16)v.x, (__bf16)v.y, (__bf16)v.z, (__bf16)v.w};
    *(uint2*)p = *(uint2*)t;
}
__device__ __forceinline__ bf16x8 ld_b64x2(const __bf16* p) {
    bf16x4 lo = *(const bf16x4*)p;
    bf16x4 hi = *(const bf16x4*)(p + 4);
    return __builtin_shufflevector(lo, hi, 0, 1, 2, 3, 4, 5, 6, 7);
}
__device__ __forceinline__ int clampl(int v) { return v < 0 ? 0 : (v > 511 ? 511 : v); }

// ---------------------------------------------------------------------------
// Init: positional encoding fp32, Fttb bf16 [m2][t], Gtb bf16 [t][m2].
// ---------------------------------------------------------------------------
__global__ __launch_bounds__(256) void k_init(float* __restrict__ pe,
                                              __bf16* __restrict__ Fttb,
                                              __bf16* __restrict__ Gtb) {
    int idx = blockIdx.x * 256 + threadIdx.x;   // 0..65535
    {
        int l = idx >> 7, d = idx & 127;
        int j = d >> 1;
        double div = exp((double)(2 * j) * (-log(10000.0) / 128.0));
        double a = (double)l * div;
        pe[idx] = (d & 1) ? (float)cos(a) : (float)sin(a);
    }
    {
        int m2 = idx >> 9, t = idx & 511;
        int m = m2 >> 1;
        int r = (m * t) & 511;
        double ang = (double)r * (6.283185307179586476925287 / 512.0);
        float cv = (float)cos(ang), sv = (float)sin(ang);
        float f = (m2 & 1) ? -sv : cv;
        Fttb[idx] = (__bf16)f;
        float s = (m == 0) ? (1.0f / 512.0f) : (2.0f / 512.0f);
        Gtb[t * 128 + m2] = (__bf16)(f * s);
    }
}

// ---------------------------------------------------------------------------
// Cast+transpose weights to bf16.
// ---------------------------------------------------------------------------
__global__ __launch_bounds__(256) void k_castw(const float* __restrict__ Wq,
                                               const float* __restrict__ Wo,
                                               const float* __restrict__ W1,
                                               const float* __restrict__ W2,
                                               const float* __restrict__ cw,
                                               __bf16* __restrict__ wbf,
                                               __bf16* __restrict__ cwtk) {
    int i = blockIdx.x * 256 + threadIdx.x;   // < 376832
    if (i < 65536) {
        int r = i & 16383, l = (i >> 14) & 1;
        int n = r >> 7, k = r & 127;
        const float* W = (i >= 32768) ? Wo : Wq;
        wbf[i] = (__bf16)W[l * 16384 + k * 128 + n];
    } else if (i < 196608) {
        int j = i - 65536;
        int l = j >> 16, r = j & 65535;
        int f = r >> 7, k = r & 127;
        wbf[i] = (__bf16)W1[l * 65536 + k * 512 + f];
    } else if (i < 327680) {
        int j = i - 196608;
        int l = j >> 16, r = j & 65535;
        int n = r >> 9, f = r & 511;
        wbf[i] = (__bf16)W2[l * 65536 + f * 128 + n];
    } else if (i < 376832) {
        int j = i - 327680;          // s*16384 + d*128 + ii
        int s = j >> 14, r = j & 16383;
        int d = r >> 7, ii = r & 127;
        cwtk[j] = (__bf16)cw[(d * 128 + ii) * 3 + s];
    }
}

// ---------------------------------------------------------------------------
// Transpose x_enc (B,D,L) fp32 -> xt (B,L,D) bf16.
// ---------------------------------------------------------------------------
__global__ __launch_bounds__(256) void k_xpose(const float* __restrict__ xe,
                                               __bf16* __restrict__ xt) {
    __shared__ float ts[128][65];
    const int b = blockIdx.y, l0 = blockIdx.x * 64;
    for (int idx = threadIdx.x; idx < 128 * 16; idx += 256) {
        int d = idx >> 4, c4 = idx & 15;
        float4 v = f4_load(&xe[((size_t)b * 128 + d) * 512 + l0 + c4 * 4]);
        ts[d][c4 * 4 + 0] = v.x; ts[d][c4 * 4 + 1] = v.y;
        ts[d][c4 * 4 + 2] = v.z; ts[d][c4 * 4 + 3] = v.w;
    }
    __syncthreads();
#pragma unroll
    for (int p = 0; p < 4; ++p) {
        int l = (threadIdx.x >> 4) + p * 16;
        int d0 = (threadIdx.x & 15) * 8;
        __bf16 tmp[8];
#pragma unroll
        for (int j = 0; j < 8; ++j) tmp[j] = (__bf16)ts[d0 + j][l];
        *(uint4*)&xt[((size_t)b * 512 + l0 + l) * 128 + d0] = *(uint4*)tmp;
    }
}

// ---------------------------------------------------------------------------
// MFMA embed, 64-row blocks: per-wave 32x64 tile.
// ---------------------------------------------------------------------------
__global__ __launch_bounds__(256, 4) void k_embed_m(const __bf16* __restrict__ xt,
                                                    const __bf16* __restrict__ cwtk,
                                                    const float* __restrict__ pe,
                                                    float* __restrict__ h,
                                                    __bf16* __restrict__ hb) {
    const int b = blockIdx.x >> 3, l0 = (blockIdx.x & 7) * 64;
    const int lane = threadIdx.x & 63, wid = threadIdx.x >> 6;
    const int wrow = (wid & 1) * 32, wcol = (wid >> 1) * 64;
    const int m16 = lane & 15, quad = lane >> 4;
    f32x4 acc[2][4];
#pragma unroll
    for (int a = 0; a < 2; ++a)
#pragma unroll
        for (int bb = 0; bb < 4; ++bb) acc[a][bb] = {0.f, 0.f, 0.f, 0.f};
#pragma unroll
    for (int s = 0; s < 3; ++s) {
#pragma unroll
        for (int ks = 0; ks < 4; ++ks) {
            const int ko = ks * 32 + quad * 8;
            bf16x8 af[2], bfr[4];
#pragma unroll
            for (int rt = 0; rt < 2; ++rt) {
                int gl = (l0 + wrow + rt * 16 + m16 + s - 1) & 511;
                af[rt] = *(const bf16x8*)&xt[(((size_t)b * 512 + gl) << 7) + ko];
            }
#pragma unroll
            for (int ct = 0; ct < 4; ++ct)
                bfr[ct] = *(const bf16x8*)&cwtk[((size_t)(s * 128 + wcol + ct * 16 + m16) << 7) + ko];
#pragma unroll
            for (int rt = 0; rt < 2; ++rt)
#pragma unroll
                for (int ct = 0; ct < 4; ++ct)
                    acc[rt][ct] = __builtin_amdgcn_mfma_f32_16x16x32_bf16(
                        af[rt], bfr[ct], acc[rt][ct], 0, 0, 0);
        }
    }
#pragma unroll
    for (int ct = 0; ct < 4; ++ct) {
        int gcol = wcol + ct * 16 + m16;
#pragma unroll
        for (int rt = 0; rt < 2; ++rt)
#pragma unroll
            for (int r = 0; r < 4; ++r) {
                int l = l0 + wrow + rt * 16 + quad * 4 + r;
                float v = acc[rt][ct][r] + pe[l * 128 + gcol];
                size_t gi = (((size_t)b * 512 + l) << 7) + gcol;
                h[gi] = v;
                hb[gi] = (__bf16)v;
            }
    }
}

// ---------------------------------------------------------------------------
// q-proj transposed, 64-row blocks: qT[n][row] = (X @ Wq + bq)^T, bf16 out.
// ---------------------------------------------------------------------------
__global__ __launch_bounds__(256, 4) void k_qprojT(const __bf16* __restrict__ Xb,
                                                   const __bf16* __restrict__ Wt,
                                                   const float* __restrict__ bias,
                                                   __bf16* __restrict__ qT) {
    const int rowBase = blockIdx.x * 64;
    const int lane = threadIdx.x & 63, wid = threadIdx.x >> 6;
    const int wn = (wid & 1) * 64, wr = (wid >> 1) * 32;
    const int m16 = lane & 15, quad = lane >> 4;
    f32x4 acc[4][2];
#pragma unroll
    for (int a = 0; a < 4; ++a)
#pragma unroll
        for (int b = 0; b < 2; ++b) acc[a][b] = {0.f, 0.f, 0.f, 0.f};
#pragma unroll
    for (int ks = 0; ks < 4; ++ks) {
        const int ko = ks * 32 + quad * 8;
        bf16x8 wf[4], xf[2];
#pragma unroll
        for (int rt = 0; rt < 4; ++rt)
            wf[rt] = *(const bf16x8*)&Wt[((size_t)(wn + rt * 16 + m16) << 7) + ko];
#pragma unroll
        for (int ct = 0; ct < 2; ++ct)
            xf[ct] = *(const bf16x8*)&Xb[((size_t)(rowBase + wr + ct * 16 + m16) << 7) + ko];
#pragma unroll
        for (int rt = 0; rt < 4; ++rt)
#pragma unroll
            for (int ct = 0; ct < 2; ++ct)
                acc[rt][ct] = __builtin_amdgcn_mfma_f32_16x16x32_bf16(
                    wf[rt], xf[ct], acc[rt][ct], 0, 0, 0);
    }
#pragma unroll
    for (int rt = 0; rt < 4; ++rt)
#pragma unroll
        for (int r = 0; r < 4; ++r) {
            int n = wn + rt * 16 + quad * 4 + r;
            float bv = bias[n];
#pragma unroll
            for (int ct = 0; ct < 2; ++ct) {
                int grow = rowBase + wr + ct * 16 + m16;
                qT[(size_t)n * 65536 + grow] = (__bf16)(acc[rt][ct][r] + bv);
            }
        }
}

// ---------------------------------------------------------------------------
// Fused forward-DFT + mode mix.
// ---------------------------------------------------------------------------
__global__ __launch_bounds__(128) void k_fdftmix(const __bf16* __restrict__ qT,
                                                 const __bf16* __restrict__ Fttb,
                                                 const float* __restrict__ fwr,
                                                 const float* __restrict__ fwi,
                                                 __bf16* __restrict__ ddb) {
    __shared__ float cs[32][CS_LD];
    const int b = blockIdx.y, d0 = blockIdx.x * 32;
    const int lane = threadIdx.x & 63, wid = threadIdx.x >> 6;
    const int wm = wid * 64;
    const int m16 = lane & 15, quad = lane >> 4;
    f32x4 acc[2][4];
#pragma unroll
    for (int a = 0; a < 2; ++a)
#pragma unroll
        for (int bb = 0; bb < 4; ++bb) acc[a][bb] = {0.f, 0.f, 0.f, 0.f};
    for (int ks = 0; ks < 16; ++ks) {
        const int ko = ks * 32 + quad * 8;
        bf16x8 af[2], bf[4];
#pragma unroll
        for (int rt = 0; rt < 2; ++rt)
            af[rt] = *(const bf16x8*)&qT[(size_t)(d0 + rt * 16 + m16) * 65536 + b * 512 + ko];
#pragma unroll
        for (int ct = 0; ct < 4; ++ct)
            bf[ct] = *(const bf16x8*)&Fttb[(size_t)(wm + ct * 16 + m16) * 512 + ko];
#pragma unroll
        for (int rt = 0; rt < 2; ++rt)
#pragma unroll
            for (int ct = 0; ct < 4; ++ct)
                acc[rt][ct] = __builtin_amdgcn_mfma_f32_16x16x32_bf16(
                    af[rt], bf[ct], acc[rt][ct], 0, 0, 0);
    }
#pragma unroll
    for (int rt = 0; rt < 2; ++rt)
#pragma unroll
        for (int ct = 0; ct < 4; ++ct)
#pragma unroll
            for (int r = 0; r < 4; ++r)
                cs[rt * 16 + quad * 4 + r][wm + ct * 16 + m16] = acc[rt][ct][r];
    __syncthreads();
    const int m = threadIdx.x & 63, og = threadIdx.x >> 6;   // og in {0,1}
#pragma unroll
    for (int lh = 0; lh < 2; ++lh) {
        int hh = (d0 >> 4) + lh;
#pragma unroll
        for (int oi = 0; oi < 8; ++oi) {
            int o = og * 8 + oi;
            float dr = 0.f, di = 0.f;
#pragma unroll
            for (int e = 0; e < 16; ++e) {
                float2 cv = *(const float2*)&cs[lh * 16 + e][2 * m];
                float wr = fwr[(((size_t)hh * 16 + e) * 16 + o) * 64 + m];
                float wi = fwi[(((size_t)hh * 16 + e) * 16 + o) * 64 + m];
                dr += cv.x * wr - cv.y * wi;
                di += cv.x * wi + cv.y * wr;
            }
            __bf16 t2[2] = {(__bf16)dr, (__bf16)di};
            *(uint*)&ddb[((size_t)b * 128 + hh * 16 + o) * 128 + 2 * m] = *(uint*)t2;
        }
    }
}

// ---------------------------------------------------------------------------
// Inverse DFT via MFMA: per-wave 64t x 32ho.
// ---------------------------------------------------------------------------
__global__ __launch_bounds__(256, 4) void k_idft_m(const __bf16* __restrict__ ddb,
                                                   const __bf16* __restrict__ Gtb,
                                                   __bf16* __restrict__ y) {
    const int b = blockIdx.y;
    const int t0 = (blockIdx.x & 3) * 128, hob = (blockIdx.x >> 2) * 64;
    const int lane = threadIdx.x & 63, wid = threadIdx.x >> 6;
    const int wt = (wid & 1) * 64, wh = (wid >> 1) * 32;
    const int m16 = lane & 15, quad = lane >> 4;
    f32x4 acc[4][2];
#pragma unroll
    for (int a = 0; a < 4; ++a)
#pragma unroll
        for (int bb = 0; bb < 2; ++bb) acc[a][bb] = {0.f, 0.f, 0.f, 0.f};
#pragma unroll
    for (int ks = 0; ks < 4; ++ks) {
        const int ko = ks * 32 + quad * 8;
        bf16x8 af[4], bf[2];
#pragma unroll
        for (int rt = 0; rt < 4; ++rt)
            af[rt] = *(const bf16x8*)&Gtb[(size_t)(t0 + wt + rt * 16 + m16) * 128 + ko];
#pragma unroll
        for (int ct = 0; ct < 2; ++ct)
            bf[ct] = *(const bf16x8*)&ddb[((size_t)b * 128 + hob + wh + ct * 16 + m16) * 128 + ko];
#pragma unroll
        for (int rt = 0; rt < 4; ++rt)
#pragma unroll
            for (int ct = 0; ct < 2; ++ct)
                acc[rt][ct] = __builtin_amdgcn_mfma_f32_16x16x32_bf16(
                    af[rt], bf[ct], acc[rt][ct], 0, 0, 0);
    }
#pragma unroll
    for (int rt = 0; rt < 4; ++rt)
#pragma unroll
        for (int ct = 0; ct < 2; ++ct) {
            int ho = hob + wh + ct * 16 + m16;
            int tb = t0 + wt + rt * 16 + quad * 4;
            __bf16 tmp[4] = {(__bf16)acc[rt][ct][0], (__bf16)acc[rt][ct][1],
                             (__bf16)acc[rt][ct][2], (__bf16)acc[rt][ct][3]};
            *(uint2*)&y[((size_t)b * 128 + ho) * 512 + tb] = *(uint2*)tmp;
        }
}

// ---------------------------------------------------------------------------
// Fused out-proj GEMM + series_decomp:
//   s[96 rows] = yb @ Wo + bo + hres  (rows l0-16..l0+79, clamped = replicate)
//   out[64 rows] = s - movmean(s,25), written fp32 + bf16, full-line stores.
// Waves: 2 row-groups (48 rows = 3 tiles) x 2 col-groups (64). LDS 49.9 KB.
// ---------------------------------------------------------------------------
__global__ __launch_bounds__(256, 3) void k_mgd(const __bf16* __restrict__ yb,
                                                const __bf16* __restrict__ Wt,
                                                const float* __restrict__ bias,
                                                const float* __restrict__ hres,
                                                float* __restrict__ outf,
                                                __bf16* __restrict__ outb) {
    __shared__ float ss[96 * SS_LD];   // 49,920 B
    const int b = blockIdx.x >> 3, l0 = (blockIdx.x & 7) * 64;
    const int lane = threadIdx.x & 63, wid = threadIdx.x >> 6;
    const int wrow = (wid & 1) * 48, wcol = (wid >> 1) * 64;
    const int m16 = lane & 15, quad = lane >> 4;
    f32x4 acc[3][4];
#pragma unroll
    for (int a = 0; a < 3; ++a)
#pragma unroll
        for (int bb = 0; bb < 4; ++bb) acc[a][bb] = {0.f, 0.f, 0.f, 0.f};
#pragma unroll
    for (int ks = 0; ks < 4; ++ks) {
        const int ko = ks * 32 + quad * 8;
        bf16x8 af[3], bfr[4];
#pragma unroll
        for (int rt = 0; rt < 3; ++rt) {
            int gl = clampl(l0 - 16 + wrow + rt * 16 + m16);
            af[rt] = *(const bf16x8*)&yb[(((size_t)b * 512 + gl) << 7) + ko];
        }
#pragma unroll
        for (int ct = 0; ct < 4; ++ct)
            bfr[ct] = *(const bf16x8*)&Wt[((size_t)(wcol + ct * 16 + m16) << 7) + ko];
#pragma unroll
        for (int rt = 0; rt < 3; ++rt)
#pragma unroll
            for (int ct = 0; ct < 4; ++ct)
                acc[rt][ct] = __builtin_amdgcn_mfma_f32_16x16x32_bf16(
                    af[rt], bfr[ct], acc[rt][ct], 0, 0, 0);
    }
    // epilogue: s = acc + bias + hres -> LDS
#pragma unroll
    for (int ct = 0; ct < 4; ++ct) {
        int col = wcol + ct * 16 + m16;
        float bv = bias[col];
#pragma unroll
        for (int rt = 0; rt < 3; ++rt)
#pragma unroll
            for (int r = 0; r < 4; ++r) {
                int row = wrow + rt * 16 + quad * 4 + r;
                int gl = clampl(l0 - 16 + row);
                ss[row * SS_LD + col] =
                    acc[rt][ct][r] + bv + hres[(((size_t)b * 512 + gl) << 7) + col];
            }
    }
    __syncthreads();
    // sliding-window decomp over LDS, coalesced f4 output
    const int dg = threadIdx.x & 31, lg = threadIdx.x >> 5;
    const int d0 = dg * 4, base = lg * 8;
    float4 s = f4_zero();
#pragma unroll
    for (int w = 0; w < 25; ++w) {
        float4 v = f4_load(&ss[(base + 4 + w) * SS_LD + d0]);
        s.x += v.x; s.y += v.y; s.z += v.z; s.w += v.w;
    }
    const float inv = 1.0f / 25.0f;
#pragma unroll
    for (int i = 0; i < 8; ++i) {
        float4 x = f4_load(&ss[(base + 16 + i) * SS_LD + d0]);
        float4 o = make_float4(x.x - s.x * inv, x.y - s.y * inv,
                               x.z - s.z * inv, x.w - s.w * inv);
        size_t gi = (((size_t)b * 512 + l0 + base + i) << 7) + d0;
        f4_store(&outf[gi], o);
        store_bf4(&outb[gi], o);
        if (i < 7) {
            float4 a = f4_load(&ss[(base + 29 + i) * SS_LD + d0]);
            float4 r = f4_load(&ss[(base + 4 + i) * SS_LD + d0]);
            s.x += a.x - r.x; s.y += a.y - r.y; s.z += a.z - r.z; s.w += a.w - r.w;
        }
    }
}

// ---------------------------------------------------------------------------
// Fused FFN + series_decomp:
//   s[96 rows] = Xf + gelu(Xb @ W1) @ W2  (halo rows clamped),
//   out[64 rows] = s - movmean(s,25). DFF in 8 chunks of 64; gelu tile ts
//   aliases the ss LDS region (dead before ss is written). LDS 49.9 KB.
// ---------------------------------------------------------------------------
__global__ __launch_bounds__(256, 3) void k_ffd(const __bf16* __restrict__ Xb,
                                                const float* __restrict__ Xf,
                                                const __bf16* __restrict__ W1t,
                                                const __bf16* __restrict__ W2t,
                                                float* __restrict__ outf,
                                                __bf16* __restrict__ outb) {
    __shared__ __align__(16) float ss[96 * SS_LD];   // 49,920 B
    __bf16* ts = (__bf16*)ss;                        // 96*68*2 = 13,056 B alias
    const int b = blockIdx.x >> 3, l0 = (blockIdx.x & 7) * 64;
    const int lane = threadIdx.x & 63, wid = threadIdx.x >> 6;
    const int wrow = (wid & 1) * 48;
    const int wcolF = (wid >> 1) * 32;   // GEMM1 cols within 64-f chunk
    const int wcolO = (wid >> 1) * 64;   // GEMM2 output cols
    const int m16 = lane & 15, quad = lane >> 4;
    f32x4 acc2[3][4];
#pragma unroll
    for (int a = 0; a < 3; ++a)
#pragma unroll
        for (int bb = 0; bb < 4; ++bb) acc2[a][bb] = {0.f, 0.f, 0.f, 0.f};

    for (int fc = 0; fc < 8; ++fc) {
        const int f0 = fc * 64;
        f32x4 c1[3][2];
#pragma unroll
        for (int a = 0; a < 3; ++a)
#pragma unroll
            for (int bb = 0; bb < 2; ++bb) c1[a][bb] = {0.f, 0.f, 0.f, 0.f};
#pragma unroll
        for (int ks = 0; ks < 4; ++ks) {
            const int ko = ks * 32 + quad * 8;
            bf16x8 af[3], bfr[2];
#pragma unroll
            for (int rt = 0; rt < 3; ++rt) {
                int gl = clampl(l0 - 16 + wrow + rt * 16 + m16);
                af[rt] = *(const bf16x8*)&Xb[(((size_t)b * 512 + gl) << 7) + ko];
            }
#pragma unroll
            for (int ct = 0; ct < 2; ++ct)
                bfr[ct] = *(const bf16x8*)&W1t[((size_t)(f0 + wcolF + ct * 16 + m16) << 7) + ko];
#pragma unroll
            for (int rt = 0; rt < 3; ++rt)
#pragma unroll
                for (int ct = 0; ct < 2; ++ct)
                    c1[rt][ct] = __builtin_amdgcn_mfma_f32_16x16x32_bf16(
                        af[rt], bfr[ct], c1[rt][ct], 0, 0, 0);
        }
#pragma unroll
        for (int rt = 0; rt < 3; ++rt)
#pragma unroll
            for (int ct = 0; ct < 2; ++ct)
#pragma unroll
                for (int r = 0; r < 4; ++r) {
                    int lrow = wrow + rt * 16 + quad * 4 + r;
                    int lcol = wcolF + ct * 16 + m16;
                    ts[lrow * TS2_LD + lcol] = (__bf16)gelu_fast(c1[rt][ct][r]);
                }
        __syncthreads();
#pragma unroll
        for (int ks2 = 0; ks2 < 2; ++ks2) {
            const int ko2 = ks2 * 32 + quad * 8;
            bf16x8 af[3], bfr[4];
#pragma unroll
            for (int rt = 0; rt < 3; ++rt)
                af[rt] = ld_b64x2(&ts[(wrow + rt * 16 + m16) * TS2_LD + ko2]);
#pragma unroll
            for (int ct = 0; ct < 4; ++ct)
                bfr[ct] = *(const bf16x8*)&W2t[((size_t)(wcolO + ct * 16 + m16) << 9) + f0 + ko2];
#pragma unroll
            for (int rt = 0; rt < 3; ++rt)
#pragma unroll
                for (int ct = 0; ct < 4; ++ct)
                    acc2[rt][ct] = __builtin_amdgcn_mfma_f32_16x16x32_bf16(
                        af[rt], bfr[ct], acc2[rt][ct], 0, 0, 0);
        }
        __syncthreads();   // also guards ts before next chunk / ss writes
    }
    // epilogue: s = acc2 + Xf -> LDS (ts region dead)
#pragma unroll
    for (int ct = 0; ct < 4; ++ct) {
        int col = wcolO + ct * 16 + m16;
#pragma unroll
        for (int rt = 0; rt < 3; ++rt)
#pragma unroll
            for (int r = 0; r < 4; ++r) {
                int row = wrow + rt * 16 + quad * 4 + r;
                int gl = clampl(l0 - 16 + row);
                ss[row * SS_LD + col] =
                    acc2[rt][ct][r] + Xf[(((size_t)b * 512 + gl) << 7) + col];
            }
    }
    __syncthreads();
    const int dg = threadIdx.x & 31, lg = threadIdx.x >> 5;
    const int d0 = dg * 4, base = lg * 8;
    float4 s = f4_zero();
#pragma unroll
    for (int w = 0; w < 25; ++w) {
        float4 v = f4_load(&ss[(base + 4 + w) * SS_LD + d0]);
        s.x += v.x; s.y += v.y; s.z += v.z; s.w += v.w;
    }
    const float inv = 1.0f / 25.0f;
#pragma unroll
    for (int i = 0; i < 8; ++i) {
        float4 x = f4_load(&ss[(base + 16 + i) * SS_LD + d0]);
        float4 o = make_float4(x.x - s.x * inv, x.y - s.y * inv,
                               x.z - s.z * inv, x.w - s.w * inv);
        size_t gi = (((size_t)b * 512 + l0 + base + i) << 7) + d0;
        f4_store(&outf[gi], o);
        store_bf4(&outb[gi], o);
        if (i < 7) {
            float4 a = f4_load(&ss[(base + 29 + i) * SS_LD + d0]);
            float4 r = f4_load(&ss[(base + 4 + i) * SS_LD + d0]);
            s.x += a.x - r.x; s.y += a.y - r.y; s.z += a.z - r.z; s.w += a.w - r.w;
        }
    }
}

// ---------------------------------------------------------------------------
// LayerNorm over D=128; one wave per row.
// ---------------------------------------------------------------------------
__global__ __launch_bounds__(256) void k_ln(const float* __restrict__ X,
                                            const float* __restrict__ g,
                                            const float* __restrict__ bb,
                                            float* __restrict__ out) {
    const int row = blockIdx.x * 4 + (threadIdx.x >> 6);
    const int lane = threadIdx.x & 63;
    float2 v = *(const float2*)&X[(size_t)row * 128 + lane * 2];
    float s = v.x + v.y, ss = v.x * v.x + v.y * v.y;
#pragma unroll
    for (int o = 32; o; o >>= 1) {
        s += __shfl_xor(s, o);
        ss += __shfl_xor(ss, o);
    }
    float mu = s * (1.0f / 128.0f);
    float var = ss * (1.0f / 128.0f) - mu * mu;
    float rstd = rsqrtf(var + 1e-5f);
    float2 gg = *(const float2*)&g[lane * 2];
    float2 bv = *(const float2*)&bb[lane * 2];
    float2 o;
    o.x = (v.x - mu) * rstd * gg.x + bv.x;
    o.y = (v.y - mu) * rstd * gg.y + bv.y;
    *(float2*)&out[(size_t)row * 128 + lane * 2] = o;
}

__global__ __launch_bounds__(128) void k_colmean(const float* __restrict__ X,
                                                 float* __restrict__ cm) {
    const int b = blockIdx.y, l0 = blockIdx.x * 64, d = threadIdx.x;
    float s = 0.f;
    for (int l = l0; l < l0 + 64; ++l) s += X[((size_t)b * 512 + l) * 128 + d];
    atomicAdd(&cm[b * 128 + d], s);
}

__global__ __launch_bounds__(128) void k_final(const float* __restrict__ hn,
                                               const float* __restrict__ cm,
                                               const float* __restrict__ mark,
                                               const float* __restrict__ pw,
                                               const float* __restrict__ pb,
                                               float* __restrict__ out) {
    const int b = blockIdx.y, l0 = blockIdx.x * 128, d = threadIdx.x;
    const float c = cm[b * 128 + d] * (1.0f / 512.0f);
    float acc = 0.f;
    for (int l = l0; l < l0 + 128; ++l) {
        float v = hn[((size_t)b * 512 + l) * 128 + d] - c;
        acc += gelu_f(v) * mark[((size_t)b * 128 + d) * 512 + l] * pw[l * 128 + d];
    }
    __shared__ float red[2];
#pragma unroll
    for (int o = 32; o; o >>= 1) acc += __shfl_xor(acc, o);
    if ((threadIdx.x & 63) == 0) red[threadIdx.x >> 6] = acc;
    __syncthreads();
    if (threadIdx.x == 0) {
        float tot = red[0] + red[1];
        if (blockIdx.x == 0) tot += pb[0];
        atomicAdd(&out[b], tot);
    }
}

// ---------------------------------------------------------------------------
extern "C" void kernel_launch(void* const* d_in, const int* in_sizes, int n_in,
                              void* d_out, int out_size, void* d_ws, size_t ws_size,
                              hipStream_t stream) {
    const float* xe   = (const float*)d_in[0];
    const float* mark = (const float*)d_in[1];
    const float* cw   = (const float*)d_in[4];
    const float* Wq   = (const float*)d_in[5];
    const float* bq   = (const float*)d_in[6];
    const float* Wo   = (const float*)d_in[7];
    const float* bo   = (const float*)d_in[8];
    const float* fwr  = (const float*)d_in[9];
    const float* fwi  = (const float*)d_in[10];
    const float* W1   = (const float*)d_in[11];
    const float* W2   = (const float*)d_in[12];
    const float* lng  = (const float*)d_in[13];
    const float* lnb  = (const float*)d_in[14];
    const float* pw   = (const float*)d_in[15];
    const float* pb   = (const float*)d_in[16];
    float* out = (float*)d_out;

    // Workspace layout (float-slot offsets). Total ~101.9 MB.
    // fp32 state ping-pongs h <-> bufA; bf16 state ping-pongs hb0 <-> hb1.
    float* ws    = (float*)d_ws;
    __bf16* Fttb = (__bf16*)ws;              // 65536 bf16
    __bf16* Gtb  = (__bf16*)(ws + 65536);    // 65536 bf16
    float* h     = ws + 131072;              // 8388608 fp32
    float* bufA  = ws + 8519680;             // 8388608 fp32 (xt|qT+ddb|h')
    __bf16* hb0  = (__bf16*)(ws + 16908288); // 8M bf16 (4M float slots)
    __bf16* hb1  = (__bf16*)(ws + 21102592); // 8M bf16
    float* yrg   = ws + 25296896;            // 4194304 (pe+cwtk | yb)
    float* cm    = ws + 29491200;            // 16384
    __bf16* wbf  = (__bf16*)(ws + 29507584); // 327680 bf16 (163840 slots)
    float* pe    = yrg;
    __bf16* cwtk = (__bf16*)(yrg + 65536);   // dead after embed
    __bf16* yb   = (__bf16*)yrg;             // overlays pe/cwtk after embed
    __bf16* xt   = (__bf16*)bufA;            // dead after embed
    __bf16* qT   = (__bf16*)bufA;            // dead after fdftmix
    __bf16* ddb  = (__bf16*)(bufA + 4194304);// dead after idft
    __bf16* Wqt  = wbf;
    __bf16* Wot  = wbf + 32768;
    __bf16* W1t  = wbf + 65536;
    __bf16* W2t  = wbf + 196608;

    k_init<<<256, 256, 0, stream>>>(pe, Fttb, Gtb);
    k_castw<<<1472, 256, 0, stream>>>(Wq, Wo, W1, W2, cw, wbf, cwtk);
    k_xpose<<<dim3(8, 128), 256, 0, stream>>>(xe, xt);
    k_embed_m<<<1024, 256, 0, stream>>>(xt, cwtk, pe, h, hb0);
    for (int l = 0; l < NLAYER; ++l) {
        // state in: h (fp32), hb0 (bf16)
        k_qprojT<<<1024, 256, 0, stream>>>(hb0, Wqt + l * 16384, bq + l * 128, qT);
        k_fdftmix<<<dim3(4, 128), 128, 0, stream>>>(qT, Fttb, fwr + l * 131072,
                                                    fwi + l * 131072, ddb);
        k_idft_m<<<dim3(8, 128), 256, 0, stream>>>(ddb, Gtb, yb);
        // h' = decomp(yb@Wo+bo+h) -> bufA (fp32) + hb1 (bf16)
        k_mgd<<<1024, 256, 0, stream>>>(yb, Wot + l * 16384, bo + l * 128,
                                        h, bufA, hb1);
        // h'' = decomp(h' + gelu(hb1@W1)@W2) -> h (fp32) + hb0 (bf16)
        k_ffd<<<1024, 256, 0, stream>>>(hb1, bufA, W1t + l * 65536,
                                        W2t + l * 65536, h, hb0);
    }
    k_ln<<<16384, 256, 0, stream>>>(h, lng, lnb, bufA);
    hipMemsetAsync(cm, 0, 16384 * sizeof(float), stream);
    k_colmean<<<dim3(8, 128), 128, 0, stream>>>(bufA, cm);
    hipMemsetAsync(d_out, 0, 128 * sizeof(float), stream);
    k_final<<<dim3(4, 128), 128, 0, stream>>>(bufA, cm, mark, pw, pb, out);

    (void)in_sizes; (void)n_in; (void)out_size; (void)ws_size;
}

// Round 9
// 620.539 us; speedup vs baseline: 1.1646x; 1.0884x over previous
//
#include <hip/hip_runtime.h>
#include <math.h>

#define DFF 512
#define NLAYER 2
#define CS_LD 130   // fdftmix c-tile stride (fp32)
#define SS_LD 130   // fused-decomp s-tile stride (fp32)
#define TS2_LD 68   // ffd gelu-tile stride (bf16)

typedef __bf16 bf16x8 __attribute__((ext_vector_type(8)));
typedef __bf16 bf16x4 __attribute__((ext_vector_type(4)));
typedef float f32x4 __attribute__((ext_vector_type(4)));

__device__ __forceinline__ float4 f4_load(const float* p) { return *(const float4*)p; }
__device__ __forceinline__ void f4_store(float* p, float4 v) { *(float4*)p = v; }
__device__ __forceinline__ float4 f4_zero() { return make_float4(0.f, 0.f, 0.f, 0.f); }
__device__ __forceinline__ float gelu_f(float x) {
    return 0.5f * x * (1.0f + erff(x * 0.70710678118654752440f));
}
// tanh-form gelu: max |err| vs exact ~3e-4; cheap (v_exp + v_rcp).
__device__ __forceinline__ float gelu_fast(float x) {
    float z = 1.5957691216f * (x + 0.044715f * x * x * x);
    float e = __expf(z);
    return x - x / (e + 1.0f);
}
__device__ __forceinline__ void store_bf4(__bf16* p, float4 v) {
    __bf16 t[4] = {(__bf16)v.x, (__bf16)v.y, (__bf16)v.z, (__bf16)v.w};
    *(uint2*)p = *(uint2*)t;
}
__device__ __forceinline__ bf16x8 ld_b64x2(const __bf16* p) {
    bf16x4 lo = *(const bf16x4*)p;
    bf16x4 hi = *(const bf16x4*)(p + 4);
    return __builtin_shufflevector(lo, hi, 0, 1, 2, 3, 4, 5, 6, 7);
}
__device__ __forceinline__ int clampl(int v) { return v < 0 ? 0 : (v > 511 ? 511 : v); }

// ---------------------------------------------------------------------------
// Init: positional encoding fp32, Fttb bf16 [m2][t], Gtb bf16 [t][m2].
// ---------------------------------------------------------------------------
__global__ __launch_bounds__(256) void k_init(float* __restrict__ pe,
                                              __bf16* __restrict__ Fttb,
                                              __bf16* __restrict__ Gtb) {
    int idx = blockIdx.x * 256 + threadIdx.x;   // 0..65535
    {
        int l = idx >> 7, d = idx & 127;
        int j = d >> 1;
        double div = exp((double)(2 * j) * (-log(10000.0) / 128.0));
        double a = (double)l * div;
        pe[idx] = (d & 1) ? (float)cos(a) : (float)sin(a);
    }
    {
        int m2 = idx >> 9, t = idx & 511;
        int m = m2 >> 1;
        int r = (m * t) & 511;
        double ang = (double)r * (6.283185307179586476925287 / 512.0);
        float cv = (float)cos(ang), sv = (float)sin(ang);
        float f = (m2 & 1) ? -sv : cv;
        Fttb[idx] = (__bf16)f;
        float s = (m == 0) ? (1.0f / 512.0f) : (2.0f / 512.0f);
        Gtb[t * 128 + m2] = (__bf16)(f * s);
    }
}

// ---------------------------------------------------------------------------
// Cast+transpose weights to bf16.
// ---------------------------------------------------------------------------
__global__ __launch_bounds__(256) void k_castw(const float* __restrict__ Wq,
                                               const float* __restrict__ Wo,
                                               const float* __restrict__ W1,
                                               const float* __restrict__ W2,
                                               const float* __restrict__ cw,
                                               __bf16* __restrict__ wbf,
                                               __bf16* __restrict__ cwtk) {
    int i = blockIdx.x * 256 + threadIdx.x;   // < 376832
    if (i < 65536) {
        int r = i & 16383, l = (i >> 14) & 1;
        int n = r >> 7, k = r & 127;
        const float* W = (i >= 32768) ? Wo : Wq;
        wbf[i] = (__bf16)W[l * 16384 + k * 128 + n];
    } else if (i < 196608) {
        int j = i - 65536;
        int l = j >> 16, r = j & 65535;
        int f = r >> 7, k = r & 127;
        wbf[i] = (__bf16)W1[l * 65536 + k * 512 + f];
    } else if (i < 327680) {
        int j = i - 196608;
        int l = j >> 16, r = j & 65535;
        int n = r >> 9, f = r & 511;
        wbf[i] = (__bf16)W2[l * 65536 + f * 128 + n];
    } else if (i < 376832) {
        int j = i - 327680;          // s*16384 + d*128 + ii
        int s = j >> 14, r = j & 16383;
        int d = r >> 7, ii = r & 127;
        cwtk[j] = (__bf16)cw[(d * 128 + ii) * 3 + s];
    }
}

// ---------------------------------------------------------------------------
// Transpose x_enc (B,D,L) fp32 -> xt (B,L,D) bf16.
// ---------------------------------------------------------------------------
__global__ __launch_bounds__(256) void k_xpose(const float* __restrict__ xe,
                                               __bf16* __restrict__ xt) {
    __shared__ float ts[128][65];
    const int b = blockIdx.y, l0 = blockIdx.x * 64;
    for (int idx = threadIdx.x; idx < 128 * 16; idx += 256) {
        int d = idx >> 4, c4 = idx & 15;
        float4 v = f4_load(&xe[((size_t)b * 128 + d) * 512 + l0 + c4 * 4]);
        ts[d][c4 * 4 + 0] = v.x; ts[d][c4 * 4 + 1] = v.y;
        ts[d][c4 * 4 + 2] = v.z; ts[d][c4 * 4 + 3] = v.w;
    }
    __syncthreads();
#pragma unroll
    for (int p = 0; p < 4; ++p) {
        int l = (threadIdx.x >> 4) + p * 16;
        int d0 = (threadIdx.x & 15) * 8;
        __bf16 tmp[8];
#pragma unroll
        for (int j = 0; j < 8; ++j) tmp[j] = (__bf16)ts[d0 + j][l];
        *(uint4*)&xt[((size_t)b * 512 + l0 + l) * 128 + d0] = *(uint4*)tmp;
    }
}

// ---------------------------------------------------------------------------
// MFMA embed, 64-row blocks: per-wave 32x64 tile.
// ---------------------------------------------------------------------------
__global__ __launch_bounds__(256, 4) void k_embed_m(const __bf16* __restrict__ xt,
                                                    const __bf16* __restrict__ cwtk,
                                                    const float* __restrict__ pe,
                                                    float* __restrict__ h,
                                                    __bf16* __restrict__ hb) {
    const int b = blockIdx.x >> 3, l0 = (blockIdx.x & 7) * 64;
    const int lane = threadIdx.x & 63, wid = threadIdx.x >> 6;
    const int wrow = (wid & 1) * 32, wcol = (wid >> 1) * 64;
    const int m16 = lane & 15, quad = lane >> 4;
    f32x4 acc[2][4];
#pragma unroll
    for (int a = 0; a < 2; ++a)
#pragma unroll
        for (int bb = 0; bb < 4; ++bb) acc[a][bb] = {0.f, 0.f, 0.f, 0.f};
#pragma unroll
    for (int s = 0; s < 3; ++s) {
#pragma unroll
        for (int ks = 0; ks < 4; ++ks) {
            const int ko = ks * 32 + quad * 8;
            bf16x8 af[2], bfr[4];
#pragma unroll
            for (int rt = 0; rt < 2; ++rt) {
                int gl = (l0 + wrow + rt * 16 + m16 + s - 1) & 511;
                af[rt] = *(const bf16x8*)&xt[(((size_t)b * 512 + gl) << 7) + ko];
            }
#pragma unroll
            for (int ct = 0; ct < 4; ++ct)
                bfr[ct] = *(const bf16x8*)&cwtk[((size_t)(s * 128 + wcol + ct * 16 + m16) << 7) + ko];
#pragma unroll
            for (int rt = 0; rt < 2; ++rt)
#pragma unroll
                for (int ct = 0; ct < 4; ++ct)
                    acc[rt][ct] = __builtin_amdgcn_mfma_f32_16x16x32_bf16(
                        af[rt], bfr[ct], acc[rt][ct], 0, 0, 0);
        }
    }
#pragma unroll
    for (int ct = 0; ct < 4; ++ct) {
        int gcol = wcol + ct * 16 + m16;
#pragma unroll
        for (int rt = 0; rt < 2; ++rt)
#pragma unroll
            for (int r = 0; r < 4; ++r) {
                int l = l0 + wrow + rt * 16 + quad * 4 + r;
                float v = acc[rt][ct][r] + pe[l * 128 + gcol];
                size_t gi = (((size_t)b * 512 + l) << 7) + gcol;
                h[gi] = v;
                hb[gi] = (__bf16)v;
            }
    }
}

// ---------------------------------------------------------------------------
// q-proj transposed, 64-row blocks: qT[n][row] = (X @ Wq + bq)^T, bf16 out.
// ---------------------------------------------------------------------------
__global__ __launch_bounds__(256, 4) void k_qprojT(const __bf16* __restrict__ Xb,
                                                   const __bf16* __restrict__ Wt,
                                                   const float* __restrict__ bias,
                                                   __bf16* __restrict__ qT) {
    const int rowBase = blockIdx.x * 64;
    const int lane = threadIdx.x & 63, wid = threadIdx.x >> 6;
    const int wn = (wid & 1) * 64, wr = (wid >> 1) * 32;
    const int m16 = lane & 15, quad = lane >> 4;
    f32x4 acc[4][2];
#pragma unroll
    for (int a = 0; a < 4; ++a)
#pragma unroll
        for (int b = 0; b < 2; ++b) acc[a][b] = {0.f, 0.f, 0.f, 0.f};
#pragma unroll
    for (int ks = 0; ks < 4; ++ks) {
        const int ko = ks * 32 + quad * 8;
        bf16x8 wf[4], xf[2];
#pragma unroll
        for (int rt = 0; rt < 4; ++rt)
            wf[rt] = *(const bf16x8*)&Wt[((size_t)(wn + rt * 16 + m16) << 7) + ko];
#pragma unroll
        for (int ct = 0; ct < 2; ++ct)
            xf[ct] = *(const bf16x8*)&Xb[((size_t)(rowBase + wr + ct * 16 + m16) << 7) + ko];
#pragma unroll
        for (int rt = 0; rt < 4; ++rt)
#pragma unroll
            for (int ct = 0; ct < 2; ++ct)
                acc[rt][ct] = __builtin_amdgcn_mfma_f32_16x16x32_bf16(
                    wf[rt], xf[ct], acc[rt][ct], 0, 0, 0);
    }
#pragma unroll
    for (int rt = 0; rt < 4; ++rt)
#pragma unroll
        for (int r = 0; r < 4; ++r) {
            int n = wn + rt * 16 + quad * 4 + r;
            float bv = bias[n];
#pragma unroll
            for (int ct = 0; ct < 2; ++ct) {
                int grow = rowBase + wr + ct * 16 + m16;
                qT[(size_t)n * 65536 + grow] = (__bf16)(acc[rt][ct][r] + bv);
            }
        }
}

// ---------------------------------------------------------------------------
// Fused forward-DFT + mode mix. 256 threads: 4 waves, per-wave 16d x 64m2
// (8 waves/CU at grid 4x128 vs 4 before).
// ---------------------------------------------------------------------------
__global__ __launch_bounds__(256) void k_fdftmix(const __bf16* __restrict__ qT,
                                                 const __bf16* __restrict__ Fttb,
                                                 const float* __restrict__ fwr,
                                                 const float* __restrict__ fwi,
                                                 __bf16* __restrict__ ddb) {
    __shared__ float cs[32][CS_LD];
    const int b = blockIdx.y, d0 = blockIdx.x * 32;
    const int lane = threadIdx.x & 63, wid = threadIdx.x >> 6;
    const int wd = (wid & 1) * 16;        // d-tile within the 32
    const int wm = (wid >> 1) * 64;       // m2 half
    const int m16 = lane & 15, quad = lane >> 4;
    f32x4 acc[4];
#pragma unroll
    for (int ct = 0; ct < 4; ++ct) acc[ct] = {0.f, 0.f, 0.f, 0.f};
    for (int ks = 0; ks < 16; ++ks) {
        const int ko = ks * 32 + quad * 8;
        bf16x8 af = *(const bf16x8*)&qT[(size_t)(d0 + wd + m16) * 65536 + b * 512 + ko];
        bf16x8 bf[4];
#pragma unroll
        for (int ct = 0; ct < 4; ++ct)
            bf[ct] = *(const bf16x8*)&Fttb[(size_t)(wm + ct * 16 + m16) * 512 + ko];
#pragma unroll
        for (int ct = 0; ct < 4; ++ct)
            acc[ct] = __builtin_amdgcn_mfma_f32_16x16x32_bf16(af, bf[ct], acc[ct], 0, 0, 0);
    }
#pragma unroll
    for (int ct = 0; ct < 4; ++ct)
#pragma unroll
        for (int r = 0; r < 4; ++r)
            cs[wd + quad * 4 + r][wm + ct * 16 + m16] = acc[ct][r];
    __syncthreads();
    // mix: 256 threads, each handles 2 heads x 4 o x 1 m
    const int m = threadIdx.x & 63, og = threadIdx.x >> 6;   // og in {0..3}
#pragma unroll
    for (int lh = 0; lh < 2; ++lh) {
        int hh = (d0 >> 4) + lh;
#pragma unroll
        for (int oi = 0; oi < 4; ++oi) {
            int o = og * 4 + oi;
            float dr = 0.f, di = 0.f;
#pragma unroll
            for (int e = 0; e < 16; ++e) {
                float2 cv = *(const float2*)&cs[lh * 16 + e][2 * m];
                float wr = fwr[(((size_t)hh * 16 + e) * 16 + o) * 64 + m];
                float wi = fwi[(((size_t)hh * 16 + e) * 16 + o) * 64 + m];
                dr += cv.x * wr - cv.y * wi;
                di += cv.x * wi + cv.y * wr;
            }
            __bf16 t2[2] = {(__bf16)dr, (__bf16)di};
            *(uint*)&ddb[((size_t)b * 128 + hh * 16 + o) * 128 + 2 * m] = *(uint*)t2;
        }
    }
}

// ---------------------------------------------------------------------------
// Inverse DFT via MFMA: per-wave 64t x 32ho.
// ---------------------------------------------------------------------------
__global__ __launch_bounds__(256, 4) void k_idft_m(const __bf16* __restrict__ ddb,
                                                   const __bf16* __restrict__ Gtb,
                                                   __bf16* __restrict__ y) {
    const int b = blockIdx.y;
    const int t0 = (blockIdx.x & 3) * 128, hob = (blockIdx.x >> 2) * 64;
    const int lane = threadIdx.x & 63, wid = threadIdx.x >> 6;
    const int wt = (wid & 1) * 64, wh = (wid >> 1) * 32;
    const int m16 = lane & 15, quad = lane >> 4;
    f32x4 acc[4][2];
#pragma unroll
    for (int a = 0; a < 4; ++a)
#pragma unroll
        for (int bb = 0; bb < 2; ++bb) acc[a][bb] = {0.f, 0.f, 0.f, 0.f};
#pragma unroll
    for (int ks = 0; ks < 4; ++ks) {
        const int ko = ks * 32 + quad * 8;
        bf16x8 af[4], bf[2];
#pragma unroll
        for (int rt = 0; rt < 4; ++rt)
            af[rt] = *(const bf16x8*)&Gtb[(size_t)(t0 + wt + rt * 16 + m16) * 128 + ko];
#pragma unroll
        for (int ct = 0; ct < 2; ++ct)
            bf[ct] = *(const bf16x8*)&ddb[((size_t)b * 128 + hob + wh + ct * 16 + m16) * 128 + ko];
#pragma unroll
        for (int rt = 0; rt < 4; ++rt)
#pragma unroll
            for (int ct = 0; ct < 2; ++ct)
                acc[rt][ct] = __builtin_amdgcn_mfma_f32_16x16x32_bf16(
                    af[rt], bf[ct], acc[rt][ct], 0, 0, 0);
    }
#pragma unroll
    for (int rt = 0; rt < 4; ++rt)
#pragma unroll
        for (int ct = 0; ct < 2; ++ct) {
            int ho = hob + wh + ct * 16 + m16;
            int tb = t0 + wt + rt * 16 + quad * 4;
            __bf16 tmp[4] = {(__bf16)acc[rt][ct][0], (__bf16)acc[rt][ct][1],
                             (__bf16)acc[rt][ct][2], (__bf16)acc[rt][ct][3]};
            *(uint2*)&y[((size_t)b * 128 + ho) * 512 + tb] = *(uint2*)tmp;
        }
}

// ---------------------------------------------------------------------------
// Fused out-proj GEMM + series_decomp. yb tile staged in LDS (aliases ss).
// ---------------------------------------------------------------------------
__global__ __launch_bounds__(256, 3) void k_mgd(const __bf16* __restrict__ yb,
                                                const __bf16* __restrict__ Wt,
                                                const float* __restrict__ bias,
                                                const float* __restrict__ hres,
                                                float* __restrict__ outf,
                                                __bf16* __restrict__ outb) {
    __shared__ __align__(16) float ss[96 * SS_LD];   // 49,920 B
    __bf16* xs = (__bf16*)ss;                        // 96x128 bf16 alias (24,576 B)
    const int b = blockIdx.x >> 3, l0 = (blockIdx.x & 7) * 64;
    // stage yb rows l0-16..l0+79 (clamped), XOR-swizzled
    for (int it = 0; it < 6; ++it) {
        int c = it * 256 + threadIdx.x;   // 0..1535
        int r = c >> 4, g = c & 15;
        int gl = clampl(l0 - 16 + r);
        *(uint4*)&xs[(r << 7) + ((g ^ (r & 7)) << 3)] =
            *(const uint4*)&yb[(((size_t)b * 512 + gl) << 7) + (g << 3)];
    }
    __syncthreads();
    const int lane = threadIdx.x & 63, wid = threadIdx.x >> 6;
    const int wrow = (wid & 1) * 48, wcol = (wid >> 1) * 64;
    const int m16 = lane & 15, quad = lane >> 4;
    f32x4 acc[3][4];
#pragma unroll
    for (int a = 0; a < 3; ++a)
#pragma unroll
        for (int bb = 0; bb < 4; ++bb) acc[a][bb] = {0.f, 0.f, 0.f, 0.f};
#pragma unroll
    for (int ks = 0; ks < 4; ++ks) {
        const int ko = ks * 32 + quad * 8;
        bf16x8 af[3], bfr[4];
#pragma unroll
        for (int rt = 0; rt < 3; ++rt) {
            int row = wrow + rt * 16 + m16;
            af[rt] = *(const bf16x8*)&xs[(row << 7) + (((ks * 4 + quad) ^ (row & 7)) << 3)];
        }
#pragma unroll
        for (int ct = 0; ct < 4; ++ct)
            bfr[ct] = *(const bf16x8*)&Wt[((size_t)(wcol + ct * 16 + m16) << 7) + ko];
#pragma unroll
        for (int rt = 0; rt < 3; ++rt)
#pragma unroll
            for (int ct = 0; ct < 4; ++ct)
                acc[rt][ct] = __builtin_amdgcn_mfma_f32_16x16x32_bf16(
                    af[rt], bfr[ct], acc[rt][ct], 0, 0, 0);
    }
    __syncthreads();   // xs dead; ss may overwrite
    // epilogue: s = acc + bias + hres -> LDS
#pragma unroll
    for (int ct = 0; ct < 4; ++ct) {
        int col = wcol + ct * 16 + m16;
        float bv = bias[col];
#pragma unroll
        for (int rt = 0; rt < 3; ++rt)
#pragma unroll
            for (int r = 0; r < 4; ++r) {
                int row = wrow + rt * 16 + quad * 4 + r;
                int gl = clampl(l0 - 16 + row);
                ss[row * SS_LD + col] =
                    acc[rt][ct][r] + bv + hres[(((size_t)b * 512 + gl) << 7) + col];
            }
    }
    __syncthreads();
    // sliding-window decomp over LDS, coalesced f4 output
    const int dg = threadIdx.x & 31, lg = threadIdx.x >> 5;
    const int d0 = dg * 4, base = lg * 8;
    float4 s = f4_zero();
#pragma unroll
    for (int w = 0; w < 25; ++w) {
        float4 v = f4_load(&ss[(base + 4 + w) * SS_LD + d0]);
        s.x += v.x; s.y += v.y; s.z += v.z; s.w += v.w;
    }
    const float inv = 1.0f / 25.0f;
#pragma unroll
    for (int i = 0; i < 8; ++i) {
        float4 x = f4_load(&ss[(base + 16 + i) * SS_LD + d0]);
        float4 o = make_float4(x.x - s.x * inv, x.y - s.y * inv,
                               x.z - s.z * inv, x.w - s.w * inv);
        size_t gi = (((size_t)b * 512 + l0 + base + i) << 7) + d0;
        f4_store(&outf[gi], o);
        store_bf4(&outb[gi], o);
        if (i < 7) {
            float4 a = f4_load(&ss[(base + 29 + i) * SS_LD + d0]);
            float4 r = f4_load(&ss[(base + 4 + i) * SS_LD + d0]);
            s.x += a.x - r.x; s.y += a.y - r.y; s.z += a.z - r.z; s.w += a.w - r.w;
        }
    }
}

// ---------------------------------------------------------------------------
// Fused FFN + series_decomp, v2: X tile LDS-staged once (kills 8x L2 re-reads),
// double-buffered gelu tile (1 barrier/chunk), all aliased under ss.
// smem: xs[0,24576) | ts0[24576,37632) | ts1[37632,50688); ss = fp32 alias.
// ---------------------------------------------------------------------------
__global__ __launch_bounds__(256, 3) void k_ffd(const __bf16* __restrict__ Xb,
                                                const float* __restrict__ Xf,
                                                const __bf16* __restrict__ W1t,
                                                const __bf16* __restrict__ W2t,
                                                float* __restrict__ outf,
                                                __bf16* __restrict__ outb) {
    __shared__ __align__(16) unsigned char smem[50688];
    float* ss = (float*)smem;                        // 96*130*4 = 49,920 B
    __bf16* xs = (__bf16*)smem;                      // 96*128*2 = 24,576 B
    const int b = blockIdx.x >> 3, l0 = (blockIdx.x & 7) * 64;
    // stage X rows l0-16..l0+79 (clamped), XOR-swizzled
    for (int it = 0; it < 6; ++it) {
        int c = it * 256 + threadIdx.x;   // 0..1535
        int r = c >> 4, g = c & 15;
        int gl = clampl(l0 - 16 + r);
        *(uint4*)&xs[(r << 7) + ((g ^ (r & 7)) << 3)] =
            *(const uint4*)&Xb[(((size_t)b * 512 + gl) << 7) + (g << 3)];
    }
    __syncthreads();
    const int lane = threadIdx.x & 63, wid = threadIdx.x >> 6;
    const int wrow = (wid & 1) * 48;
    const int wcolF = (wid >> 1) * 32;   // GEMM1 cols within 64-f chunk
    const int wcolO = (wid >> 1) * 64;   // GEMM2 output cols
    const int m16 = lane & 15, quad = lane >> 4;
    f32x4 acc2[3][4];
#pragma unroll
    for (int a = 0; a < 3; ++a)
#pragma unroll
        for (int bb = 0; bb < 4; ++bb) acc2[a][bb] = {0.f, 0.f, 0.f, 0.f};

    for (int fc = 0; fc < 8; ++fc) {
        __bf16* ts = (__bf16*)(smem + 24576 + (fc & 1) * 13056);
        const int f0 = fc * 64;
        f32x4 c1[3][2];
#pragma unroll
        for (int a = 0; a < 3; ++a)
#pragma unroll
            for (int bb = 0; bb < 2; ++bb) c1[a][bb] = {0.f, 0.f, 0.f, 0.f};
#pragma unroll
        for (int ks = 0; ks < 4; ++ks) {
            const int ko = ks * 32 + quad * 8;
            bf16x8 af[3], bfr[2];
#pragma unroll
            for (int rt = 0; rt < 3; ++rt) {
                int row = wrow + rt * 16 + m16;
                af[rt] = *(const bf16x8*)&xs[(row << 7) + (((ks * 4 + quad) ^ (row & 7)) << 3)];
            }
#pragma unroll
            for (int ct = 0; ct < 2; ++ct)
                bfr[ct] = *(const bf16x8*)&W1t[((size_t)(f0 + wcolF + ct * 16 + m16) << 7) + ko];
#pragma unroll
            for (int rt = 0; rt < 3; ++rt)
#pragma unroll
                for (int ct = 0; ct < 2; ++ct)
                    c1[rt][ct] = __builtin_amdgcn_mfma_f32_16x16x32_bf16(
                        af[rt], bfr[ct], c1[rt][ct], 0, 0, 0);
        }
#pragma unroll
        for (int rt = 0; rt < 3; ++rt)
#pragma unroll
            for (int ct = 0; ct < 2; ++ct)
#pragma unroll
                for (int r = 0; r < 4; ++r) {
                    int lrow = wrow + rt * 16 + quad * 4 + r;
                    int lcol = wcolF + ct * 16 + m16;
                    ts[lrow * TS2_LD + lcol] = (__bf16)gelu_fast(c1[rt][ct][r]);
                }
        __syncthreads();   // ts[fc&1] write -> read; also fences prior-buffer laps
#pragma unroll
        for (int ks2 = 0; ks2 < 2; ++ks2) {
            const int ko2 = ks2 * 32 + quad * 8;
            bf16x8 af[3], bfr[4];
#pragma unroll
            for (int rt = 0; rt < 3; ++rt)
                af[rt] = ld_b64x2(&ts[(wrow + rt * 16 + m16) * TS2_LD + ko2]);
#pragma unroll
            for (int ct = 0; ct < 4; ++ct)
                bfr[ct] = *(const bf16x8*)&W2t[((size_t)(wcolO + ct * 16 + m16) << 9) + f0 + ko2];
#pragma unroll
            for (int rt = 0; rt < 3; ++rt)
#pragma unroll
                for (int ct = 0; ct < 4; ++ct)
                    acc2[rt][ct] = __builtin_amdgcn_mfma_f32_16x16x32_bf16(
                        af[rt], bfr[ct], acc2[rt][ct], 0, 0, 0);
        }
        // no trailing barrier: next chunk writes the OTHER ts buffer
    }
    __syncthreads();   // all xs/ts reads done; ss may overwrite
    // epilogue: s = acc2 + Xf -> LDS
#pragma unroll
    for (int ct = 0; ct < 4; ++ct) {
        int col = wcolO + ct * 16 + m16;
#pragma unroll
        for (int rt = 0; rt < 3; ++rt)
#pragma unroll
            for (int r = 0; r < 4; ++r) {
                int row = wrow + rt * 16 + quad * 4 + r;
                int gl = clampl(l0 - 16 + row);
                ss[row * SS_LD + col] =
                    acc2[rt][ct][r] + Xf[(((size_t)b * 512 + gl) << 7) + col];
            }
    }
    __syncthreads();
    const int dg = threadIdx.x & 31, lg = threadIdx.x >> 5;
    const int d0 = dg * 4, base = lg * 8;
    float4 s = f4_zero();
#pragma unroll
    for (int w = 0; w < 25; ++w) {
        float4 v = f4_load(&ss[(base + 4 + w) * SS_LD + d0]);
        s.x += v.x; s.y += v.y; s.z += v.z; s.w += v.w;
    }
    const float inv = 1.0f / 25.0f;
#pragma unroll
    for (int i = 0; i < 8; ++i) {
        float4 x = f4_load(&ss[(base + 16 + i) * SS_LD + d0]);
        float4 o = make_float4(x.x - s.x * inv, x.y - s.y * inv,
                               x.z - s.z * inv, x.w - s.w * inv);
        size_t gi = (((size_t)b * 512 + l0 + base + i) << 7) + d0;
        f4_store(&outf[gi], o);
        store_bf4(&outb[gi], o);
        if (i < 7) {
            float4 a = f4_load(&ss[(base + 29 + i) * SS_LD + d0]);
            float4 r = f4_load(&ss[(base + 4 + i) * SS_LD + d0]);
            s.x += a.x - r.x; s.y += a.y - r.y; s.z += a.z - r.z; s.w += a.w - r.w;
        }
    }
}

// ---------------------------------------------------------------------------
// LayerNorm over D=128; one wave per row.
// ---------------------------------------------------------------------------
__global__ __launch_bounds__(256) void k_ln(const float* __restrict__ X,
                                            const float* __restrict__ g,
                                            const float* __restrict__ bb,
                                            float* __restrict__ out) {
    const int row = blockIdx.x * 4 + (threadIdx.x >> 6);
    const int lane = threadIdx.x & 63;
    float2 v = *(const float2*)&X[(size_t)row * 128 + lane * 2];
    float s = v.x + v.y, ss = v.x * v.x + v.y * v.y;
#pragma unroll
    for (int o = 32; o; o >>= 1) {
        s += __shfl_xor(s, o);
        ss += __shfl_xor(ss, o);
    }
    float mu = s * (1.0f / 128.0f);
    float var = ss * (1.0f / 128.0f) - mu * mu;
    float rstd = rsqrtf(var + 1e-5f);
    float2 gg = *(const float2*)&g[lane * 2];
    float2 bv = *(const float2*)&bb[lane * 2];
    float2 o;
    o.x = (v.x - mu) * rstd * gg.x + bv.x;
    o.y = (v.y - mu) * rstd * gg.y + bv.y;
    *(float2*)&out[(size_t)row * 128 + lane * 2] = o;
}

__global__ __launch_bounds__(128) void k_colmean(const float* __restrict__ X,
                                                 float* __restrict__ cm) {
    const int b = blockIdx.y, l0 = blockIdx.x * 64, d = threadIdx.x;
    float s = 0.f;
    for (int l = l0; l < l0 + 64; ++l) s += X[((size_t)b * 512 + l) * 128 + d];
    atomicAdd(&cm[b * 128 + d], s);
}

__global__ __launch_bounds__(128) void k_final(const float* __restrict__ hn,
                                               const float* __restrict__ cm,
                                               const float* __restrict__ mark,
                                               const float* __restrict__ pw,
                                               const float* __restrict__ pb,
                                               float* __restrict__ out) {
    const int b = blockIdx.y, l0 = blockIdx.x * 128, d = threadIdx.x;
    const float c = cm[b * 128 + d] * (1.0f / 512.0f);
    float acc = 0.f;
    for (int l = l0; l < l0 + 128; ++l) {
        float v = hn[((size_t)b * 512 + l) * 128 + d] - c;
        acc += gelu_f(v) * mark[((size_t)b * 128 + d) * 512 + l] * pw[l * 128 + d];
    }
    __shared__ float red[2];
#pragma unroll
    for (int o = 32; o; o >>= 1) acc += __shfl_xor(acc, o);
    if ((threadIdx.x & 63) == 0) red[threadIdx.x >> 6] = acc;
    __syncthreads();
    if (threadIdx.x == 0) {
        float tot = red[0] + red[1];
        if (blockIdx.x == 0) tot += pb[0];
        atomicAdd(&out[b], tot);
    }
}

// ---------------------------------------------------------------------------
extern "C" void kernel_launch(void* const* d_in, const int* in_sizes, int n_in,
                              void* d_out, int out_size, void* d_ws, size_t ws_size,
                              hipStream_t stream) {
    const float* xe   = (const float*)d_in[0];
    const float* mark = (const float*)d_in[1];
    const float* cw   = (const float*)d_in[4];
    const float* Wq   = (const float*)d_in[5];
    const float* bq   = (const float*)d_in[6];
    const float* Wo   = (const float*)d_in[7];
    const float* bo   = (const float*)d_in[8];
    const float* fwr  = (const float*)d_in[9];
    const float* fwi  = (const float*)d_in[10];
    const float* W1   = (const float*)d_in[11];
    const float* W2   = (const float*)d_in[12];
    const float* lng  = (const float*)d_in[13];
    const float* lnb  = (const float*)d_in[14];
    const float* pw   = (const float*)d_in[15];
    const float* pb   = (const float*)d_in[16];
    float* out = (float*)d_out;

    // Workspace layout (float-slot offsets). Total ~118 MB.
    float* ws    = (float*)d_ws;
    __bf16* Fttb = (__bf16*)ws;              // 65536 bf16
    __bf16* Gtb  = (__bf16*)(ws + 65536);    // 65536 bf16
    float* h     = ws + 131072;              // 8388608 fp32
    float* bufA  = ws + 8519680;             // 8388608 fp32 (xt|qT+ddb|h')
    __bf16* hb0  = (__bf16*)(ws + 16908288); // 8M bf16
    __bf16* hb1  = (__bf16*)(ws + 21102592); // 8M bf16
    float* yrg   = ws + 25296896;            // 4194304 (pe+cwtk | yb)
    float* cm    = ws + 29491200;            // 16384
    __bf16* wbf  = (__bf16*)(ws + 29507584); // 327680 bf16
    float* pe    = yrg;
    __bf16* cwtk = (__bf16*)(yrg + 65536);   // dead after embed
    __bf16* yb   = (__bf16*)yrg;             // overlays pe/cwtk after embed
    __bf16* xt   = (__bf16*)bufA;            // dead after embed
    __bf16* qT   = (__bf16*)bufA;            // dead after fdftmix
    __bf16* ddb  = (__bf16*)(bufA + 4194304);// dead after idft
    __bf16* Wqt  = wbf;
    __bf16* Wot  = wbf + 32768;
    __bf16* W1t  = wbf + 65536;
    __bf16* W2t  = wbf + 196608;

    k_init<<<256, 256, 0, stream>>>(pe, Fttb, Gtb);
    k_castw<<<1472, 256, 0, stream>>>(Wq, Wo, W1, W2, cw, wbf, cwtk);
    k_xpose<<<dim3(8, 128), 256, 0, stream>>>(xe, xt);
    k_embed_m<<<1024, 256, 0, stream>>>(xt, cwtk, pe, h, hb0);
    for (int l = 0; l < NLAYER; ++l) {
        k_qprojT<<<1024, 256, 0, stream>>>(hb0, Wqt + l * 16384, bq + l * 128, qT);
        k_fdftmix<<<dim3(4, 128), 256, 0, stream>>>(qT, Fttb, fwr + l * 131072,
                                                    fwi + l * 131072, ddb);
        k_idft_m<<<dim3(8, 128), 256, 0, stream>>>(ddb, Gtb, yb);
        k_mgd<<<1024, 256, 0, stream>>>(yb, Wot + l * 16384, bo + l * 128,
                                        h, bufA, hb1);
        k_ffd<<<1024, 256, 0, stream>>>(hb1, bufA, W1t + l * 65536,
                                        W2t + l * 65536, h, hb0);
    }
    k_ln<<<16384, 256, 0, stream>>>(h, lng, lnb, bufA);
    hipMemsetAsync(cm, 0, 16384 * sizeof(float), stream);
    k_colmean<<<dim3(8, 128), 128, 0, stream>>>(bufA, cm);
    hipMemsetAsync(d_out, 0, 128 * sizeof(float), stream);
    k_final<<<dim3(4, 128), 128, 0, stream>>>(bufA, cm, mark, pw, pb, out);

    (void)in_sizes; (void)n_in; (void)out_size; (void)ws_size;
}

// Round 10
// 617.522 us; speedup vs baseline: 1.1703x; 1.0049x over previous
//
#include <hip/hip_runtime.h>
#include <math.h>

#define DFF 512
#define NLAYER 2
#define CS_LD 130   // fdftmix c-tile stride (fp32)
#define SS_LD 130   // fused-decomp s-tile stride (fp32)
#define TS2_LD 68   // ffd gelu-tile stride (bf16)

typedef __bf16 bf16x8 __attribute__((ext_vector_type(8)));
typedef __bf16 bf16x4 __attribute__((ext_vector_type(4)));
typedef float f32x4 __attribute__((ext_vector_type(4)));

__device__ __forceinline__ float4 f4_load(const float* p) { return *(const float4*)p; }
__device__ __forceinline__ void f4_store(float* p, float4 v) { *(float4*)p = v; }
__device__ __forceinline__ float4 f4_zero() { return make_float4(0.f, 0.f, 0.f, 0.f); }
__device__ __forceinline__ float gelu_f(float x) {
    return 0.5f * x * (1.0f + erff(x * 0.70710678118654752440f));
}
// tanh-form gelu: max |err| vs exact ~3e-4; cheap (v_exp + v_rcp).
__device__ __forceinline__ float gelu_fast(float x) {
    float z = 1.5957691216f * (x + 0.044715f * x * x * x);
    float e = __expf(z);
    return x - x / (e + 1.0f);
}
__device__ __forceinline__ void store_bf4(__bf16* p, float4 v) {
    __bf16 t[4] = {(__bf16)v.x, (__bf16)v.y, (__bf16)v.z, (__bf16)v.w};
    *(uint2*)p = *(uint2*)t;
}
__device__ __forceinline__ bf16x8 ld_b64x2(const __bf16* p) {
    bf16x4 lo = *(const bf16x4*)p;
    bf16x4 hi = *(const bf16x4*)(p + 4);
    return __builtin_shufflevector(lo, hi, 0, 1, 2, 3, 4, 5, 6, 7);
}
__device__ __forceinline__ int clampl(int v) { return v < 0 ? 0 : (v > 511 ? 511 : v); }
// scalar read from the XOR-swizzled 128-col bf16 tile
__device__ __forceinline__ int sw_idx(int row, int col) {
    return (row << 7) + ((((col >> 3) ^ (row & 7)) << 3) | (col & 7));
}

// ---------------------------------------------------------------------------
// Init: positional encoding fp32, Fttb bf16 [m2][t], Gtb bf16 [t][m2].
// ---------------------------------------------------------------------------
__global__ __launch_bounds__(256) void k_init(float* __restrict__ pe,
                                              __bf16* __restrict__ Fttb,
                                              __bf16* __restrict__ Gtb) {
    int idx = blockIdx.x * 256 + threadIdx.x;   // 0..65535
    {
        int l = idx >> 7, d = idx & 127;
        int j = d >> 1;
        double div = exp((double)(2 * j) * (-log(10000.0) / 128.0));
        double a = (double)l * div;
        pe[idx] = (d & 1) ? (float)cos(a) : (float)sin(a);
    }
    {
        int m2 = idx >> 9, t = idx & 511;
        int m = m2 >> 1;
        int r = (m * t) & 511;
        double ang = (double)r * (6.283185307179586476925287 / 512.0);
        float cv = (float)cos(ang), sv = (float)sin(ang);
        float f = (m2 & 1) ? -sv : cv;
        Fttb[idx] = (__bf16)f;
        float s = (m == 0) ? (1.0f / 512.0f) : (2.0f / 512.0f);
        Gtb[t * 128 + m2] = (__bf16)(f * s);
    }
}

// ---------------------------------------------------------------------------
// Cast+transpose weights to bf16.
// ---------------------------------------------------------------------------
__global__ __launch_bounds__(256) void k_castw(const float* __restrict__ Wq,
                                               const float* __restrict__ Wo,
                                               const float* __restrict__ W1,
                                               const float* __restrict__ W2,
                                               const float* __restrict__ cw,
                                               __bf16* __restrict__ wbf,
                                               __bf16* __restrict__ cwtk) {
    int i = blockIdx.x * 256 + threadIdx.x;   // < 376832
    if (i < 65536) {
        int r = i & 16383, l = (i >> 14) & 1;
        int n = r >> 7, k = r & 127;
        const float* W = (i >= 32768) ? Wo : Wq;
        wbf[i] = (__bf16)W[l * 16384 + k * 128 + n];
    } else if (i < 196608) {
        int j = i - 65536;
        int l = j >> 16, r = j & 65535;
        int f = r >> 7, k = r & 127;
        wbf[i] = (__bf16)W1[l * 65536 + k * 512 + f];
    } else if (i < 327680) {
        int j = i - 196608;
        int l = j >> 16, r = j & 65535;
        int n = r >> 9, f = r & 511;
        wbf[i] = (__bf16)W2[l * 65536 + f * 128 + n];
    } else if (i < 376832) {
        int j = i - 327680;          // s*16384 + d*128 + ii
        int s = j >> 14, r = j & 16383;
        int d = r >> 7, ii = r & 127;
        cwtk[j] = (__bf16)cw[(d * 128 + ii) * 3 + s];
    }
}

// ---------------------------------------------------------------------------
// Transpose x_enc (B,D,L) fp32 -> xt (B,L,D) bf16.
// ---------------------------------------------------------------------------
__global__ __launch_bounds__(256) void k_xpose(const float* __restrict__ xe,
                                               __bf16* __restrict__ xt) {
    __shared__ float ts[128][65];
    const int b = blockIdx.y, l0 = blockIdx.x * 64;
    for (int idx = threadIdx.x; idx < 128 * 16; idx += 256) {
        int d = idx >> 4, c4 = idx & 15;
        float4 v = f4_load(&xe[((size_t)b * 128 + d) * 512 + l0 + c4 * 4]);
        ts[d][c4 * 4 + 0] = v.x; ts[d][c4 * 4 + 1] = v.y;
        ts[d][c4 * 4 + 2] = v.z; ts[d][c4 * 4 + 3] = v.w;
    }
    __syncthreads();
#pragma unroll
    for (int p = 0; p < 4; ++p) {
        int l = (threadIdx.x >> 4) + p * 16;
        int d0 = (threadIdx.x & 15) * 8;
        __bf16 tmp[8];
#pragma unroll
        for (int j = 0; j < 8; ++j) tmp[j] = (__bf16)ts[d0 + j][l];
        *(uint4*)&xt[((size_t)b * 512 + l0 + l) * 128 + d0] = *(uint4*)tmp;
    }
}

// ---------------------------------------------------------------------------
// MFMA embed, 64-row blocks: per-wave 32x64 tile.
// ---------------------------------------------------------------------------
__global__ __launch_bounds__(256, 4) void k_embed_m(const __bf16* __restrict__ xt,
                                                    const __bf16* __restrict__ cwtk,
                                                    const float* __restrict__ pe,
                                                    float* __restrict__ h,
                                                    __bf16* __restrict__ hb) {
    const int b = blockIdx.x >> 3, l0 = (blockIdx.x & 7) * 64;
    const int lane = threadIdx.x & 63, wid = threadIdx.x >> 6;
    const int wrow = (wid & 1) * 32, wcol = (wid >> 1) * 64;
    const int m16 = lane & 15, quad = lane >> 4;
    f32x4 acc[2][4];
#pragma unroll
    for (int a = 0; a < 2; ++a)
#pragma unroll
        for (int bb = 0; bb < 4; ++bb) acc[a][bb] = {0.f, 0.f, 0.f, 0.f};
#pragma unroll
    for (int s = 0; s < 3; ++s) {
#pragma unroll
        for (int ks = 0; ks < 4; ++ks) {
            const int ko = ks * 32 + quad * 8;
            bf16x8 af[2], bfr[4];
#pragma unroll
            for (int rt = 0; rt < 2; ++rt) {
                int gl = (l0 + wrow + rt * 16 + m16 + s - 1) & 511;
                af[rt] = *(const bf16x8*)&xt[(((size_t)b * 512 + gl) << 7) + ko];
            }
#pragma unroll
            for (int ct = 0; ct < 4; ++ct)
                bfr[ct] = *(const bf16x8*)&cwtk[((size_t)(s * 128 + wcol + ct * 16 + m16) << 7) + ko];
#pragma unroll
            for (int rt = 0; rt < 2; ++rt)
#pragma unroll
                for (int ct = 0; ct < 4; ++ct)
                    acc[rt][ct] = __builtin_amdgcn_mfma_f32_16x16x32_bf16(
                        af[rt], bfr[ct], acc[rt][ct], 0, 0, 0);
        }
    }
#pragma unroll
    for (int ct = 0; ct < 4; ++ct) {
        int gcol = wcol + ct * 16 + m16;
#pragma unroll
        for (int rt = 0; rt < 2; ++rt)
#pragma unroll
            for (int r = 0; r < 4; ++r) {
                int l = l0 + wrow + rt * 16 + quad * 4 + r;
                float v = acc[rt][ct][r] + pe[l * 128 + gcol];
                size_t gi = (((size_t)b * 512 + l) << 7) + gcol;
                h[gi] = v;
                hb[gi] = (__bf16)v;
            }
    }
}

// ---------------------------------------------------------------------------
// q-proj transposed, 64-row blocks: qT[n][row] = (X @ Wq + bq)^T, bf16 out.
// ---------------------------------------------------------------------------
__global__ __launch_bounds__(256, 4) void k_qprojT(const __bf16* __restrict__ Xb,
                                                   const __bf16* __restrict__ Wt,
                                                   const float* __restrict__ bias,
                                                   __bf16* __restrict__ qT) {
    const int rowBase = blockIdx.x * 64;
    const int lane = threadIdx.x & 63, wid = threadIdx.x >> 6;
    const int wn = (wid & 1) * 64, wr = (wid >> 1) * 32;
    const int m16 = lane & 15, quad = lane >> 4;
    f32x4 acc[4][2];
#pragma unroll
    for (int a = 0; a < 4; ++a)
#pragma unroll
        for (int b = 0; b < 2; ++b) acc[a][b] = {0.f, 0.f, 0.f, 0.f};
#pragma unroll
    for (int ks = 0; ks < 4; ++ks) {
        const int ko = ks * 32 + quad * 8;
        bf16x8 wf[4], xf[2];
#pragma unroll
        for (int rt = 0; rt < 4; ++rt)
            wf[rt] = *(const bf16x8*)&Wt[((size_t)(wn + rt * 16 + m16) << 7) + ko];
#pragma unroll
        for (int ct = 0; ct < 2; ++ct)
            xf[ct] = *(const bf16x8*)&Xb[((size_t)(rowBase + wr + ct * 16 + m16) << 7) + ko];
#pragma unroll
        for (int rt = 0; rt < 4; ++rt)
#pragma unroll
            for (int ct = 0; ct < 2; ++ct)
                acc[rt][ct] = __builtin_amdgcn_mfma_f32_16x16x32_bf16(
                    wf[rt], xf[ct], acc[rt][ct], 0, 0, 0);
    }
#pragma unroll
    for (int rt = 0; rt < 4; ++rt)
#pragma unroll
        for (int r = 0; r < 4; ++r) {
            int n = wn + rt * 16 + quad * 4 + r;
            float bv = bias[n];
#pragma unroll
            for (int ct = 0; ct < 2; ++ct) {
                int grow = rowBase + wr + ct * 16 + m16;
                qT[(size_t)n * 65536 + grow] = (__bf16)(acc[rt][ct][r] + bv);
            }
        }
}

// ---------------------------------------------------------------------------
// Fused forward-DFT + mode mix. 256 threads: 4 waves, per-wave 16d x 64m2.
// ---------------------------------------------------------------------------
__global__ __launch_bounds__(256) void k_fdftmix(const __bf16* __restrict__ qT,
                                                 const __bf16* __restrict__ Fttb,
                                                 const float* __restrict__ fwr,
                                                 const float* __restrict__ fwi,
                                                 __bf16* __restrict__ ddb) {
    __shared__ float cs[32][CS_LD];
    const int b = blockIdx.y, d0 = blockIdx.x * 32;
    const int lane = threadIdx.x & 63, wid = threadIdx.x >> 6;
    const int wd = (wid & 1) * 16;        // d-tile within the 32
    const int wm = (wid >> 1) * 64;       // m2 half
    const int m16 = lane & 15, quad = lane >> 4;
    f32x4 acc[4];
#pragma unroll
    for (int ct = 0; ct < 4; ++ct) acc[ct] = {0.f, 0.f, 0.f, 0.f};
    for (int ks = 0; ks < 16; ++ks) {
        const int ko = ks * 32 + quad * 8;
        bf16x8 af = *(const bf16x8*)&qT[(size_t)(d0 + wd + m16) * 65536 + b * 512 + ko];
        bf16x8 bf[4];
#pragma unroll
        for (int ct = 0; ct < 4; ++ct)
            bf[ct] = *(const bf16x8*)&Fttb[(size_t)(wm + ct * 16 + m16) * 512 + ko];
#pragma unroll
        for (int ct = 0; ct < 4; ++ct)
            acc[ct] = __builtin_amdgcn_mfma_f32_16x16x32_bf16(af, bf[ct], acc[ct], 0, 0, 0);
    }
#pragma unroll
    for (int ct = 0; ct < 4; ++ct)
#pragma unroll
        for (int r = 0; r < 4; ++r)
            cs[wd + quad * 4 + r][wm + ct * 16 + m16] = acc[ct][r];
    __syncthreads();
    const int m = threadIdx.x & 63, og = threadIdx.x >> 6;   // og in {0..3}
#pragma unroll
    for (int lh = 0; lh < 2; ++lh) {
        int hh = (d0 >> 4) + lh;
#pragma unroll
        for (int oi = 0; oi < 4; ++oi) {
            int o = og * 4 + oi;
            float dr = 0.f, di = 0.f;
#pragma unroll
            for (int e = 0; e < 16; ++e) {
                float2 cv = *(const float2*)&cs[lh * 16 + e][2 * m];
                float wr = fwr[(((size_t)hh * 16 + e) * 16 + o) * 64 + m];
                float wi = fwi[(((size_t)hh * 16 + e) * 16 + o) * 64 + m];
                dr += cv.x * wr - cv.y * wi;
                di += cv.x * wi + cv.y * wr;
            }
            __bf16 t2[2] = {(__bf16)dr, (__bf16)di};
            *(uint*)&ddb[((size_t)b * 128 + hh * 16 + o) * 128 + 2 * m] = *(uint*)t2;
        }
    }
}

// ---------------------------------------------------------------------------
// Inverse DFT via MFMA: per-wave 64t x 32ho.
// ---------------------------------------------------------------------------
__global__ __launch_bounds__(256, 4) void k_idft_m(const __bf16* __restrict__ ddb,
                                                   const __bf16* __restrict__ Gtb,
                                                   __bf16* __restrict__ y) {
    const int b = blockIdx.y;
    const int t0 = (blockIdx.x & 3) * 128, hob = (blockIdx.x >> 2) * 64;
    const int lane = threadIdx.x & 63, wid = threadIdx.x >> 6;
    const int wt = (wid & 1) * 64, wh = (wid >> 1) * 32;
    const int m16 = lane & 15, quad = lane >> 4;
    f32x4 acc[4][2];
#pragma unroll
    for (int a = 0; a < 4; ++a)
#pragma unroll
        for (int bb = 0; bb < 2; ++bb) acc[a][bb] = {0.f, 0.f, 0.f, 0.f};
#pragma unroll
    for (int ks = 0; ks < 4; ++ks) {
        const int ko = ks * 32 + quad * 8;
        bf16x8 af[4], bf[2];
#pragma unroll
        for (int rt = 0; rt < 4; ++rt)
            af[rt] = *(const bf16x8*)&Gtb[(size_t)(t0 + wt + rt * 16 + m16) * 128 + ko];
#pragma unroll
        for (int ct = 0; ct < 2; ++ct)
            bf[ct] = *(const bf16x8*)&ddb[((size_t)b * 128 + hob + wh + ct * 16 + m16) * 128 + ko];
#pragma unroll
        for (int rt = 0; rt < 4; ++rt)
#pragma unroll
            for (int ct = 0; ct < 2; ++ct)
                acc[rt][ct] = __builtin_amdgcn_mfma_f32_16x16x32_bf16(
                    af[rt], bf[ct], acc[rt][ct], 0, 0, 0);
    }
#pragma unroll
    for (int rt = 0; rt < 4; ++rt)
#pragma unroll
        for (int ct = 0; ct < 2; ++ct) {
            int ho = hob + wh + ct * 16 + m16;
            int tb = t0 + wt + rt * 16 + quad * 4;
            __bf16 tmp[4] = {(__bf16)acc[rt][ct][0], (__bf16)acc[rt][ct][1],
                             (__bf16)acc[rt][ct][2], (__bf16)acc[rt][ct][3]};
            *(uint2*)&y[((size_t)b * 128 + ho) * 512 + tb] = *(uint2*)tmp;
        }
}

// ---------------------------------------------------------------------------
// Fused out-proj GEMM + series_decomp. yb tile staged in LDS (aliases ss).
// hres (fp32 residual) prefetched to registers at kernel start — the barriers
// between load and use prevent the compiler from sinking the loads (R7 lesson:
// no barrier => sunk). Writes ONLY bf16 output (fp32 dropped; ffd uses bf16
// residual from its own staged tile).
// ---------------------------------------------------------------------------
__global__ __launch_bounds__(256, 3) void k_mgd(const __bf16* __restrict__ yb,
                                                const __bf16* __restrict__ Wt,
                                                const float* __restrict__ bias,
                                                const float* __restrict__ hres,
                                                __bf16* __restrict__ outb) {
    __shared__ __align__(16) float ss[96 * SS_LD];   // 49,920 B
    __bf16* xs = (__bf16*)ss;                        // 96x128 bf16 alias
    const int b = blockIdx.x >> 3, l0 = (blockIdx.x & 7) * 64;
    const int lane = threadIdx.x & 63, wid = threadIdx.x >> 6;
    const int wrow = (wid & 1) * 48, wcol = (wid >> 1) * 64;
    const int m16 = lane & 15, quad = lane >> 4;
    // prefetch residuals (global fp32) early; consumed in the epilogue
    float hr[3][4][4];
#pragma unroll
    for (int rt = 0; rt < 3; ++rt)
#pragma unroll
        for (int ct = 0; ct < 4; ++ct)
#pragma unroll
            for (int r = 0; r < 4; ++r) {
                int row = wrow + rt * 16 + quad * 4 + r;
                int gl = clampl(l0 - 16 + row);
                hr[rt][ct][r] = hres[(((size_t)b * 512 + gl) << 7) + wcol + ct * 16 + m16];
            }
    // stage yb rows l0-16..l0+79 (clamped), XOR-swizzled
    for (int it = 0; it < 6; ++it) {
        int c = it * 256 + threadIdx.x;   // 0..1535
        int r = c >> 4, g = c & 15;
        int gl = clampl(l0 - 16 + r);
        *(uint4*)&xs[(r << 7) + ((g ^ (r & 7)) << 3)] =
            *(const uint4*)&yb[(((size_t)b * 512 + gl) << 7) + (g << 3)];
    }
    __syncthreads();
    f32x4 acc[3][4];
#pragma unroll
    for (int a = 0; a < 3; ++a)
#pragma unroll
        for (int bb = 0; bb < 4; ++bb) acc[a][bb] = {0.f, 0.f, 0.f, 0.f};
#pragma unroll
    for (int ks = 0; ks < 4; ++ks) {
        const int ko = ks * 32 + quad * 8;
        bf16x8 af[3], bfr[4];
#pragma unroll
        for (int rt = 0; rt < 3; ++rt) {
            int row = wrow + rt * 16 + m16;
            af[rt] = *(const bf16x8*)&xs[(row << 7) + (((ks * 4 + quad) ^ (row & 7)) << 3)];
        }
#pragma unroll
        for (int ct = 0; ct < 4; ++ct)
            bfr[ct] = *(const bf16x8*)&Wt[((size_t)(wcol + ct * 16 + m16) << 7) + ko];
#pragma unroll
        for (int rt = 0; rt < 3; ++rt)
#pragma unroll
            for (int ct = 0; ct < 4; ++ct)
                acc[rt][ct] = __builtin_amdgcn_mfma_f32_16x16x32_bf16(
                    af[rt], bfr[ct], acc[rt][ct], 0, 0, 0);
    }
    __syncthreads();   // xs dead; ss may overwrite
    // epilogue: s = acc + bias + hres(reg) -> LDS
#pragma unroll
    for (int ct = 0; ct < 4; ++ct) {
        int col = wcol + ct * 16 + m16;
        float bv = bias[col];
#pragma unroll
        for (int rt = 0; rt < 3; ++rt)
#pragma unroll
            for (int r = 0; r < 4; ++r) {
                int row = wrow + rt * 16 + quad * 4 + r;
                ss[row * SS_LD + col] = acc[rt][ct][r] + bv + hr[rt][ct][r];
            }
    }
    __syncthreads();
    // sliding-window decomp over LDS, coalesced bf16 output
    const int dg = threadIdx.x & 31, lg = threadIdx.x >> 5;
    const int d0 = dg * 4, base = lg * 8;
    float4 s = f4_zero();
#pragma unroll
    for (int w = 0; w < 25; ++w) {
        float4 v = f4_load(&ss[(base + 4 + w) * SS_LD + d0]);
        s.x += v.x; s.y += v.y; s.z += v.z; s.w += v.w;
    }
    const float inv = 1.0f / 25.0f;
#pragma unroll
    for (int i = 0; i < 8; ++i) {
        float4 x = f4_load(&ss[(base + 16 + i) * SS_LD + d0]);
        float4 o = make_float4(x.x - s.x * inv, x.y - s.y * inv,
                               x.z - s.z * inv, x.w - s.w * inv);
        size_t gi = (((size_t)b * 512 + l0 + base + i) << 7) + d0;
        store_bf4(&outb[gi], o);
        if (i < 7) {
            float4 a = f4_load(&ss[(base + 29 + i) * SS_LD + d0]);
            float4 r = f4_load(&ss[(base + 4 + i) * SS_LD + d0]);
            s.x += a.x - r.x; s.y += a.y - r.y; s.z += a.z - r.z; s.w += a.w - r.w;
        }
    }
}

// ---------------------------------------------------------------------------
// Fused FFN + series_decomp, v3: residual taken from the STAGED bf16 X tile
// (no fp32 Xf global read). Residuals pulled LDS->reg after the GEMM loop,
// then a barrier, then ss overwrites the aliased region.
// smem: xs[0,24576) | ts0[24576,37632) | ts1[37632,50688); ss = fp32 alias.
// ---------------------------------------------------------------------------
__global__ __launch_bounds__(256, 3) void k_ffd(const __bf16* __restrict__ Xb,
                                                const __bf16* __restrict__ W1t,
                                                const __bf16* __restrict__ W2t,
                                                float* __restrict__ outf,
                                                __bf16* __restrict__ outb) {
    __shared__ __align__(16) unsigned char smem[50688];
    float* ss = (float*)smem;                        // 96*130*4 = 49,920 B
    __bf16* xs = (__bf16*)smem;                      // 96*128*2 = 24,576 B
    const int b = blockIdx.x >> 3, l0 = (blockIdx.x & 7) * 64;
    // stage X rows l0-16..l0+79 (clamped), XOR-swizzled
    for (int it = 0; it < 6; ++it) {
        int c = it * 256 + threadIdx.x;   // 0..1535
        int r = c >> 4, g = c & 15;
        int gl = clampl(l0 - 16 + r);
        *(uint4*)&xs[(r << 7) + ((g ^ (r & 7)) << 3)] =
            *(const uint4*)&Xb[(((size_t)b * 512 + gl) << 7) + (g << 3)];
    }
    __syncthreads();
    const int lane = threadIdx.x & 63, wid = threadIdx.x >> 6;
    const int wrow = (wid & 1) * 48;
    const int wcolF = (wid >> 1) * 32;   // GEMM1 cols within 64-f chunk
    const int wcolO = (wid >> 1) * 64;   // GEMM2 output cols
    const int m16 = lane & 15, quad = lane >> 4;
    f32x4 acc2[3][4];
#pragma unroll
    for (int a = 0; a < 3; ++a)
#pragma unroll
        for (int bb = 0; bb < 4; ++bb) acc2[a][bb] = {0.f, 0.f, 0.f, 0.f};

    for (int fc = 0; fc < 8; ++fc) {
        __bf16* ts = (__bf16*)(smem + 24576 + (fc & 1) * 13056);
        const int f0 = fc * 64;
        f32x4 c1[3][2];
#pragma unroll
        for (int a = 0; a < 3; ++a)
#pragma unroll
            for (int bb = 0; bb < 2; ++bb) c1[a][bb] = {0.f, 0.f, 0.f, 0.f};
#pragma unroll
        for (int ks = 0; ks < 4; ++ks) {
            const int ko = ks * 32 + quad * 8;
            bf16x8 af[3], bfr[2];
#pragma unroll
            for (int rt = 0; rt < 3; ++rt) {
                int row = wrow + rt * 16 + m16;
                af[rt] = *(const bf16x8*)&xs[(row << 7) + (((ks * 4 + quad) ^ (row & 7)) << 3)];
            }
#pragma unroll
            for (int ct = 0; ct < 2; ++ct)
                bfr[ct] = *(const bf16x8*)&W1t[((size_t)(f0 + wcolF + ct * 16 + m16) << 7) + ko];
#pragma unroll
            for (int rt = 0; rt < 3; ++rt)
#pragma unroll
                for (int ct = 0; ct < 2; ++ct)
                    c1[rt][ct] = __builtin_amdgcn_mfma_f32_16x16x32_bf16(
                        af[rt], bfr[ct], c1[rt][ct], 0, 0, 0);
        }
#pragma unroll
        for (int rt = 0; rt < 3; ++rt)
#pragma unroll
            for (int ct = 0; ct < 2; ++ct)
#pragma unroll
                for (int r = 0; r < 4; ++r) {
                    int lrow = wrow + rt * 16 + quad * 4 + r;
                    int lcol = wcolF + ct * 16 + m16;
                    ts[lrow * TS2_LD + lcol] = (__bf16)gelu_fast(c1[rt][ct][r]);
                }
        __syncthreads();
#pragma unroll
        for (int ks2 = 0; ks2 < 2; ++ks2) {
            const int ko2 = ks2 * 32 + quad * 8;
            bf16x8 af[3], bfr[4];
#pragma unroll
            for (int rt = 0; rt < 3; ++rt)
                af[rt] = ld_b64x2(&ts[(wrow + rt * 16 + m16) * TS2_LD + ko2]);
#pragma unroll
            for (int ct = 0; ct < 4; ++ct)
                bfr[ct] = *(const bf16x8*)&W2t[((size_t)(wcolO + ct * 16 + m16) << 9) + f0 + ko2];
#pragma unroll
            for (int rt = 0; rt < 3; ++rt)
#pragma unroll
                for (int ct = 0; ct < 4; ++ct)
                    acc2[rt][ct] = __builtin_amdgcn_mfma_f32_16x16x32_bf16(
                        af[rt], bfr[ct], acc2[rt][ct], 0, 0, 0);
        }
        // no trailing barrier: next chunk writes the OTHER ts buffer
    }
    // residuals: xs -> registers BEFORE ss (aliased) is written
    float xres[3][4][4];
#pragma unroll
    for (int rt = 0; rt < 3; ++rt)
#pragma unroll
        for (int ct = 0; ct < 4; ++ct)
#pragma unroll
            for (int r = 0; r < 4; ++r) {
                int row = wrow + rt * 16 + quad * 4 + r;
                int col = wcolO + ct * 16 + m16;
                xres[rt][ct][r] = (float)xs[sw_idx(row, col)];
            }
    __syncthreads();   // all xs/ts reads complete; ss may overwrite
    // epilogue: s = acc2 + residual -> LDS
#pragma unroll
    for (int ct = 0; ct < 4; ++ct) {
        int col = wcolO + ct * 16 + m16;
#pragma unroll
        for (int rt = 0; rt < 3; ++rt)
#pragma unroll
            for (int r = 0; r < 4; ++r) {
                int row = wrow + rt * 16 + quad * 4 + r;
                ss[row * SS_LD + col] = acc2[rt][ct][r] + xres[rt][ct][r];
            }
    }
    __syncthreads();
    const int dg = threadIdx.x & 31, lg = threadIdx.x >> 5;
    const int d0 = dg * 4, base = lg * 8;
    float4 s = f4_zero();
#pragma unroll
    for (int w = 0; w < 25; ++w) {
        float4 v = f4_load(&ss[(base + 4 + w) * SS_LD + d0]);
        s.x += v.x; s.y += v.y; s.z += v.z; s.w += v.w;
    }
    const float inv = 1.0f / 25.0f;
#pragma unroll
    for (int i = 0; i < 8; ++i) {
        float4 x = f4_load(&ss[(base + 16 + i) * SS_LD + d0]);
        float4 o = make_float4(x.x - s.x * inv, x.y - s.y * inv,
                               x.z - s.z * inv, x.w - s.w * inv);
        size_t gi = (((size_t)b * 512 + l0 + base + i) << 7) + d0;
        f4_store(&outf[gi], o);
        store_bf4(&outb[gi], o);
        if (i < 7) {
            float4 a = f4_load(&ss[(base + 29 + i) * SS_LD + d0]);
            float4 r = f4_load(&ss[(base + 4 + i) * SS_LD + d0]);
            s.x += a.x - r.x; s.y += a.y - r.y; s.z += a.z - r.z; s.w += a.w - r.w;
        }
    }
}

// ---------------------------------------------------------------------------
// LayerNorm over D=128; one wave per row.
// ---------------------------------------------------------------------------
__global__ __launch_bounds__(256) void k_ln(const float* __restrict__ X,
                                            const float* __restrict__ g,
                                            const float* __restrict__ bb,
                                            float* __restrict__ out) {
    const int row = blockIdx.x * 4 + (threadIdx.x >> 6);
    const int lane = threadIdx.x & 63;
    float2 v = *(const float2*)&X[(size_t)row * 128 + lane * 2];
    float s = v.x + v.y, ss = v.x * v.x + v.y * v.y;
#pragma unroll
    for (int o = 32; o; o >>= 1) {
        s += __shfl_xor(s, o);
        ss += __shfl_xor(ss, o);
    }
    float mu = s * (1.0f / 128.0f);
    float var = ss * (1.0f / 128.0f) - mu * mu;
    float rstd = rsqrtf(var + 1e-5f);
    float2 gg = *(const float2*)&g[lane * 2];
    float2 bv = *(const float2*)&bb[lane * 2];
    float2 o;
    o.x = (v.x - mu) * rstd * gg.x + bv.x;
    o.y = (v.y - mu) * rstd * gg.y + bv.y;
    *(float2*)&out[(size_t)row * 128 + lane * 2] = o;
}

__global__ __launch_bounds__(128) void k_colmean(const float* __restrict__ X,
                                                 float* __restrict__ cm) {
    const int b = blockIdx.y, l0 = blockIdx.x * 64, d = threadIdx.x;
    float s = 0.f;
    for (int l = l0; l < l0 + 64; ++l) s += X[((size_t)b * 512 + l) * 128 + d];
    atomicAdd(&cm[b * 128 + d], s);
}

__global__ __launch_bounds__(128) void k_final(const float* __restrict__ hn,
                                               const float* __restrict__ cm,
                                               const float* __restrict__ mark,
                                               const float* __restrict__ pw,
                                               const float* __restrict__ pb,
                                               float* __restrict__ out) {
    const int b = blockIdx.y, l0 = blockIdx.x * 128, d = threadIdx.x;
    const float c = cm[b * 128 + d] * (1.0f / 512.0f);
    float acc = 0.f;
    for (int l = l0; l < l0 + 128; ++l) {
        float v = hn[((size_t)b * 512 + l) * 128 + d] - c;
        acc += gelu_f(v) * mark[((size_t)b * 128 + d) * 512 + l] * pw[l * 128 + d];
    }
    __shared__ float red[2];
#pragma unroll
    for (int o = 32; o; o >>= 1) acc += __shfl_xor(acc, o);
    if ((threadIdx.x & 63) == 0) red[threadIdx.x >> 6] = acc;
    __syncthreads();
    if (threadIdx.x == 0) {
        float tot = red[0] + red[1];
        if (blockIdx.x == 0) tot += pb[0];
        atomicAdd(&out[b], tot);
    }
}

// ---------------------------------------------------------------------------
extern "C" void kernel_launch(void* const* d_in, const int* in_sizes, int n_in,
                              void* d_out, int out_size, void* d_ws, size_t ws_size,
                              hipStream_t stream) {
    const float* xe   = (const float*)d_in[0];
    const float* mark = (const float*)d_in[1];
    const float* cw   = (const float*)d_in[4];
    const float* Wq   = (const float*)d_in[5];
    const float* bq   = (const float*)d_in[6];
    const float* Wo   = (const float*)d_in[7];
    const float* bo   = (const float*)d_in[8];
    const float* fwr  = (const float*)d_in[9];
    const float* fwi  = (const float*)d_in[10];
    const float* W1   = (const float*)d_in[11];
    const float* W2   = (const float*)d_in[12];
    const float* lng  = (const float*)d_in[13];
    const float* lnb  = (const float*)d_in[14];
    const float* pw   = (const float*)d_in[15];
    const float* pb   = (const float*)d_in[16];
    float* out = (float*)d_out;

    // Workspace layout (float-slot offsets). Total ~118 MB.
    float* ws    = (float*)d_ws;
    __bf16* Fttb = (__bf16*)ws;              // 65536 bf16
    __bf16* Gtb  = (__bf16*)(ws + 65536);    // 65536 bf16
    float* h     = ws + 131072;              // 8388608 fp32
    float* bufA  = ws + 8519680;             // 8388608 fp32 (xt|qT+ddb|hn)
    __bf16* hb0  = (__bf16*)(ws + 16908288); // 8M bf16
    __bf16* hb1  = (__bf16*)(ws + 21102592); // 8M bf16
    float* yrg   = ws + 25296896;            // 4194304 (pe+cwtk | yb)
    float* cm    = ws + 29491200;            // 16384
    __bf16* wbf  = (__bf16*)(ws + 29507584); // 327680 bf16
    float* pe    = yrg;
    __bf16* cwtk = (__bf16*)(yrg + 65536);   // dead after embed
    __bf16* yb   = (__bf16*)yrg;             // overlays pe/cwtk after embed
    __bf16* xt   = (__bf16*)bufA;            // dead after embed
    __bf16* qT   = (__bf16*)bufA;            // dead after fdftmix
    __bf16* ddb  = (__bf16*)(bufA + 4194304);// dead after idft
    __bf16* Wqt  = wbf;
    __bf16* Wot  = wbf + 32768;
    __bf16* W1t  = wbf + 65536;
    __bf16* W2t  = wbf + 196608;

    k_init<<<256, 256, 0, stream>>>(pe, Fttb, Gtb);
    k_castw<<<1472, 256, 0, stream>>>(Wq, Wo, W1, W2, cw, wbf, cwtk);
    k_xpose<<<dim3(8, 128), 256, 0, stream>>>(xe, xt);
    k_embed_m<<<1024, 256, 0, stream>>>(xt, cwtk, pe, h, hb0);
    for (int l = 0; l < NLAYER; ++l) {
        // state in: h (fp32 residual), hb0 (bf16)
        k_qprojT<<<1024, 256, 0, stream>>>(hb0, Wqt + l * 16384, bq + l * 128, qT);
        k_fdftmix<<<dim3(4, 128), 256, 0, stream>>>(qT, Fttb, fwr + l * 131072,
                                                    fwi + l * 131072, ddb);
        k_idft_m<<<dim3(8, 128), 256, 0, stream>>>(ddb, Gtb, yb);
        // hb1 = decomp(yb@Wo+bo+h)  (bf16 only)
        k_mgd<<<1024, 256, 0, stream>>>(yb, Wot + l * 16384, bo + l * 128,
                                        h, hb1);
        // h/hb0 = decomp(hb1 + gelu(hb1@W1)@W2)
        k_ffd<<<1024, 256, 0, stream>>>(hb1, W1t + l * 65536,
                                        W2t + l * 65536, h, hb0);
    }
    k_ln<<<16384, 256, 0, stream>>>(h, lng, lnb, bufA);
    hipMemsetAsync(cm, 0, 16384 * sizeof(float), stream);
    k_colmean<<<dim3(8, 128), 128, 0, stream>>>(bufA, cm);
    hipMemsetAsync(d_out, 0, 128 * sizeof(float), stream);
    k_final<<<dim3(4, 128), 128, 0, stream>>>(bufA, cm, mark, pw, pb, out);

    (void)in_sizes; (void)n_in; (void)out_size; (void)ws_size;
}